// Round 6
// baseline (1463.191 us; speedup 1.0000x reference)
//
#include <hip/hip_runtime.h>
#include <math.h>

// Model: review-based recommender. ALL float tensors fp32.
// Shapes: VOCAB=20000, D=100, H=100, K=3, N_U=N_I=256, R=8, S=52, Sp=50, E=20000.
// Outputs (fp32, flat): pred_r[20000] @0, pred_c[20000] @20000,
//                       z_u[102400] @40000, z_i[102400] @142400.
//
// R6: conv on MFMA (bf16 Xhi*Whi, K=320 padded, per-instance 4mt x 7nt x 10kt)
// + fp32 exact recompute of z-logits with |logit| < 1e-2 (k_refine), which
// also patches zdot. c never materialized: z-logit & col-max from acc regs.

typedef __attribute__((ext_vector_type(8))) short short8;
typedef __attribute__((ext_vector_type(4))) float f32x4;

__device__ __forceinline__ float sigmoidf_(float x) { return 1.f / (1.f + expf(-x)); }
__device__ __forceinline__ ushort f2b(float f) {
    union { float f; unsigned int i; } c; c.f = f;
    unsigned int x = c.i;
    return (ushort)((x + 0x7fffu + ((x >> 16) & 1u)) >> 16);
}

#define Z_REFINE_DELTA 1e-2f
#define FLAG_CAP 204800

// ---------------------------------------------------------------------------
// K0: prep. Wt[kk=300][h=100] (fp32, for refine); fc2t[h][dd]; zero Psum;
// wpack: bf16 B-fragment layout [kt=10][nt=7][lane=64][j=8],
//        value = bf16(W'[kk][h]), kk=kt*32+(lane>>4)*8+j, h=nt*16+(lane&15),
//        zero when kk>=300 or h>=100; zero flag counter.
__global__ void k_prep(const float* __restrict__ conv_w, const float* __restrict__ fc_w2_w,
                       float* __restrict__ Wt, float* __restrict__ fc2t,
                       float* __restrict__ Psum, ushort* __restrict__ wpack,
                       int* __restrict__ flag_cnt) {
    int idx = blockIdx.x * 256 + threadIdx.x;
    if (idx < 30000) {
        int kk = idx / 100, h = idx - kk * 100;
        Wt[idx] = conv_w[h * 300 + kk];
    } else if (idx < 40000) {
        int j = idx - 30000;
        int h = j / 100, dd = j - h * 100;
        fc2t[j] = fc_w2_w[dd * 100 + h];
    } else if (idx < 91200) {
        Psum[idx - 40000] = 0.f;
    } else if (idx < 127040) {
        int j = idx - 91200;                   // [0, 35840)
        int frag = j >> 9, within = j & 511;
        int l = within >> 3, jj = within & 7;
        int kt = frag / 7, nt = frag % 7;
        int kk = kt * 32 + ((l >> 4) << 3) + jj;
        int h  = nt * 16 + (l & 15);
        ushort v = 0;
        if (kk < 300 && h < 100) v = f2b(conv_w[h * 300 + kk]);
        wpack[j] = v;
    } else if (idx == 127040) {
        *flag_cnt = 0;
    }
}

// ---------------------------------------------------------------------------
// K1: 192 threads = 3 waves; wave w owns instance gi = blockIdx*3 + w.
// Per wave: gather emb->bf16 LDS, MFMA conv (acc in regs), epilogue from regs.
__global__ __launch_bounds__(192, 2)
void k_branch(const int* __restrict__ u_rev, const int* __restrict__ i_rev,
              const float* __restrict__ emb, const ushort* __restrict__ wpack,
              const float* __restrict__ conv_b, const float* __restrict__ fc_w_w,
              const float* __restrict__ fc_w_b, const float* __restrict__ fc_w2_b,
              const float* __restrict__ fc2t, const float* __restrict__ h_r_w,
              const float* __restrict__ h_c_w,
              float* __restrict__ Pbuf, float* __restrict__ Psum,
              float* __restrict__ zdot, float* __restrict__ Pdot,
              float* __restrict__ z_out, int* __restrict__ flag_cnt,
              int* __restrict__ flag_list) {
    __shared__ __align__(16) char smem[50816];
    ushort* embf = (ushort*)smem;                    // [3][6656] bf16 X (zero-padded)
    ushort* wbuf = (ushort*)(smem + 39936);          // [3584] one kt-chunk of B-frags
    int*    s_tok = (int*)(smem + 47104);            // [3][52]
    float*  s_max = (float*)(smem + 47728);          // [3][100]
    float*  s_z   = (float*)(smem + 48928);          // [3][52]
    float*  s_P   = (float*)(smem + 49552);          // [3][100]

    const int tid = threadIdx.x, lane = tid & 63, w = tid >> 6;
    const int gi = blockIdx.x * 3 + w;
    const bool valid = gi < 4096;
    const int branch = (gi >> 11) & 1, inst = gi & 2047;
    ushort* embw = embf + w * 6656;

    // --- staging regs for W kt-chunk (448 uint4 per chunk; 3 slots/thread)
    const uint4* wp4 = (const uint4*)wpack;
    uint4* wbuf4 = (uint4*)wbuf;
    uint4 st[3];
    {
#pragma unroll
        for (int k = 0; k < 3; k++) {
            int idx = tid + 192 * k;
            if (idx < 448) st[k] = wp4[idx];         // kt = 0
        }
    }

    // --- per-wave gather: tokens, then emb rows fp32 -> bf16 LDS
    if (valid) {
        const int* rev = branch ? i_rev : u_rev;
        if (lane < 52) s_tok[w * 52 + lane] = rev[inst * 52 + lane];
        const float4* emb4 = (const float4*)emb;
        for (int idx = lane; idx < 1300; idx += 64) {
            int s = idx / 25, c = idx - s * 25;
            float4 v = emb4[s_tok[w * 52 + s] * 25 + c];
            uint2 o;
            o.x = (unsigned)f2b(v.x) | ((unsigned)f2b(v.y) << 16);
            o.y = (unsigned)f2b(v.z) | ((unsigned)f2b(v.w) << 16);
            *(uint2*)(embw + idx * 4) = o;
        }
        for (int idx = 1300 + lane; idx < 1664; idx += 64) {
            uint2 o; o.x = 0u; o.y = 0u;
            *(uint2*)(embw + idx * 4) = o;           // zero-pad [5200,6656)
        }
    }

    // write kt=0 chunk, preload kt=1
    {
#pragma unroll
        for (int k = 0; k < 3; k++) {
            int idx = tid + 192 * k;
            if (idx < 448) wbuf4[idx] = st[k];
        }
#pragma unroll
        for (int k = 0; k < 3; k++) {
            int idx = tid + 192 * k;
            if (idx < 448) st[k] = wp4[448 + idx];   // kt = 1
        }
    }
    __syncthreads();

    f32x4 acc[4][7];
#pragma unroll
    for (int mt = 0; mt < 4; mt++)
#pragma unroll
        for (int nt = 0; nt < 7; nt++) acc[mt][nt] = (f32x4){0.f, 0.f, 0.f, 0.f};

    const int col = lane & 15, quad = lane >> 4;

    for (int kt = 0; kt < 10; kt++) {
        if (valid) {
            union AU { short8 s8; uint2 u2[2]; } a[4];
            const int q8 = quad << 3;
#pragma unroll
            for (int mt = 0; mt < 4; mt++) {
                int e0 = (mt * 16 + col) * 100 + kt * 32 + q8;
                a[mt].u2[0] = *(const uint2*)(embw + e0);
                a[mt].u2[1] = *(const uint2*)(embw + e0 + 4);
            }
#pragma unroll
            for (int nt = 0; nt < 7; nt++) {
                union BU { short8 s8; uint4 u4; } b;
                b.u4 = wbuf4[nt * 64 + lane];
                acc[0][nt] = __builtin_amdgcn_mfma_f32_16x16x32_bf16(a[0].s8, b.s8, acc[0][nt], 0, 0, 0);
                acc[1][nt] = __builtin_amdgcn_mfma_f32_16x16x32_bf16(a[1].s8, b.s8, acc[1][nt], 0, 0, 0);
                acc[2][nt] = __builtin_amdgcn_mfma_f32_16x16x32_bf16(a[2].s8, b.s8, acc[2][nt], 0, 0, 0);
                acc[3][nt] = __builtin_amdgcn_mfma_f32_16x16x32_bf16(a[3].s8, b.s8, acc[3][nt], 0, 0, 0);
            }
        }
        __syncthreads();                             // all wbuf reads for kt done
        if (kt < 9) {
#pragma unroll
            for (int k = 0; k < 3; k++) {
                int idx = tid + 192 * k;
                if (idx < 448) wbuf4[idx] = st[k];   // kt+1 (loaded a full kt ago)
            }
            if (kt < 8) {
#pragma unroll
                for (int k = 0; k < 3; k++) {
                    int idx = tid + 192 * k;
                    if (idx < 448) st[k] = wp4[(kt + 2) * 448 + idx];
                }
            }
            __syncthreads();                         // wbuf(kt+1) visible
        }
    }

    if (!valid) return;                              // no more barriers below

    // --- epilogue (wave-local). C/D layout: n=col, m-row = quad*4+j [m89/m91].
    float cb[7], fw[7], vmax[7];
#pragma unroll
    for (int nt = 0; nt < 7; nt++) {
        int h = nt * 16 + col;
        cb[nt] = (h < 100) ? conv_b[h] : 0.f;
        fw[nt] = (h < 100) ? fc_w_w[h] : 0.f;
        vmax[nt] = 0.f;
    }
    const float fcb = fc_w_b[0];

#pragma unroll
    for (int mt = 0; mt < 4; mt++) {
#pragma unroll
        for (int j = 0; j < 4; j++) {
            int p = mt * 16 + quad * 4 + j;
            bool pv = p < 50;
            float part = 0.f;
#pragma unroll
            for (int nt = 0; nt < 7; nt++) {
                float c = acc[mt][nt][j] + cb[nt];
                c = c > 0.f ? c : 0.f;
                part += c * fw[nt];
                if (pv) vmax[nt] = fmaxf(vmax[nt], c);
            }
            part += __shfl_xor(part, 1, 64);
            part += __shfl_xor(part, 2, 64);
            part += __shfl_xor(part, 4, 64);
            part += __shfl_xor(part, 8, 64);
            if (pv && col == 0) {
                float logit = part + fcb;
                float z = rintf(sigmoidf_(logit));
                s_z[w * 52 + p] = z;
                z_out[branch * 102400 + inst * 50 + p] = z;
                if (fabsf(logit) < Z_REFINE_DELTA) {
                    int k = atomicAdd(flag_cnt, 1);
                    if (k < FLAG_CAP) flag_list[k] = gi * 50 + p;
                }
            }
        }
    }

    // column max: reduce over quads (lanes ^16, ^32)
#pragma unroll
    for (int nt = 0; nt < 7; nt++) {
        float m = vmax[nt];
        m = fmaxf(m, __shfl_xor(m, 16, 64));
        m = fmaxf(m, __shfl_xor(m, 32, 64));
        int h = nt * 16 + col;
        if (quad == 0 && h < 100) s_max[w * 100 + h] = m;
    }

    // P[dd] = fc_w2_b + cmax . fc2t[:,dd]; also Psum atomicAdd (r5-verified)
    if (lane < 50) {
        float a0 = fc_w2_b[lane], a1 = fc_w2_b[lane + 50];
        for (int h = 0; h < 100; h++) {
            float mx = s_max[w * 100 + h];
            a0 += mx * fc2t[h * 100 + lane];
            a1 += mx * fc2t[h * 100 + lane + 50];
        }
        Pbuf[gi * 100 + lane] = a0;
        Pbuf[gi * 100 + lane + 50] = a1;
        s_P[w * 100 + lane] = a0;
        s_P[w * 100 + lane + 50] = a1;
        atomicAdd(&Psum[(branch * 256 + (inst >> 3)) * 100 + lane], a0);
        atomicAdd(&Psum[(branch * 256 + (inst >> 3)) * 100 + lane + 50], a1);
    }

    // zdot / Pdot: wave-local butterflies (r2 order)
    {
        float v = (lane < 50) ? s_z[w * 52 + lane] * h_r_w[branch * 50 + lane] : 0.f;
        for (int s = 1; s < 64; s <<= 1) v += __shfl_xor(v, s, 64);
        if (lane == 0) zdot[gi] = v;
        float u = 0.f;
        if (lane < 50) u = s_P[w * 100 + lane] * h_c_w[branch * 100 + lane]
                         + s_P[w * 100 + lane + 50] * h_c_w[branch * 100 + lane + 50];
        for (int s = 1; s < 64; s <<= 1) u += __shfl_xor(u, s, 64);
        if (lane == 0) Pdot[gi] = u;
    }
}

// ---------------------------------------------------------------------------
// K2: exact fp32 recompute of flagged z-logits; patch z_out and zdot.
__launch_bounds__(256)
__global__ void k_refine(const int* __restrict__ u_rev, const int* __restrict__ i_rev,
                         const float* __restrict__ emb, const float* __restrict__ Wt,
                         const float* __restrict__ conv_b, const float* __restrict__ fc_w_w,
                         const float* __restrict__ fc_w_b, const float* __restrict__ h_r_w,
                         const int* __restrict__ flag_cnt, const int* __restrict__ flag_list,
                         float* __restrict__ z_out, float* __restrict__ zdot) {
    int n = *flag_cnt; if (n > FLAG_CAP) n = FLAG_CAP;
    const int lane = threadIdx.x & 63;
    const int wid = (blockIdx.x * 256 + threadIdx.x) >> 6;
    const int nw = gridDim.x * 4;
    for (int e = wid; e < n; e += nw) {
        int code = flag_list[e];
        int gi = code / 50, pos = code - gi * 50;
        int branch = gi >> 11, inst = gi & 2047;
        const int* rev = branch ? i_rev : u_rev;
        float c0 = 0.f, c1 = 0.f;
        if (lane < 50) { c0 = conv_b[lane]; c1 = conv_b[lane + 50]; }
#pragma unroll 1
        for (int r = 0; r < 3; r++) {
            const float* xr = emb + rev[inst * 52 + pos + r] * 100;
            const float* wr = Wt + r * 100 * 100;
            for (int d = 0; d < 100; d++) {
                float x = xr[d];
                if (lane < 50) {
                    c0 += x * wr[d * 100 + lane];
                    c1 += x * wr[d * 100 + lane + 50];
                }
            }
        }
        float v = 0.f;
        if (lane < 50)
            v = fmaxf(c0, 0.f) * fc_w_w[lane] + fmaxf(c1, 0.f) * fc_w_w[lane + 50];
        for (int s = 1; s < 64; s <<= 1) v += __shfl_xor(v, s, 64);
        if (lane == 0) {
            float z = rintf(sigmoidf_(v + fc_w_b[0]));
            float old = z_out[branch * 102400 + inst * 50 + pos];
            if (z != old) {
                z_out[branch * 102400 + inst * 50 + pos] = z;
                atomicAdd(&zdot[gi], (z - old) * h_r_w[branch * 50 + pos]);
            }
        }
    }
}

// ---------------------------------------------------------------------------
// K3: per-edge (unchanged from r5, verified absmax 0.0).
__launch_bounds__(256)
__global__ void k_edge(const int* __restrict__ uid, const int* __restrict__ iid,
                       const float* __restrict__ Pbuf, const float* __restrict__ Psum,
                       const float* __restrict__ zdot, const float* __restrict__ Pdot,
                       const float* __restrict__ user_bias, const float* __restrict__ item_bias,
                       const float* __restrict__ global_bias, float* __restrict__ out) {
    int wave = threadIdx.x >> 6, lane = threadIdx.x & 63;
    int e = blockIdx.x * 4 + wave;
    int u = uid[e], i = iid[e];
    int g = lane >> 2, q = lane & 3;
    const float4* prow4; const float4* psum4; float wr, wc;
    if (g < 8) {
        prow4 = (const float4*)(Pbuf + (u * 8 + g) * 100);
        psum4 = (const float4*)(Psum + 25600 + i * 100);
        wr = zdot[u * 8 + g]; wc = Pdot[u * 8 + g];
    } else {
        prow4 = (const float4*)(Pbuf + (2048 + i * 8 + (g - 8)) * 100);
        psum4 = (const float4*)(Psum + u * 100);
        wr = zdot[2048 + i * 8 + (g - 8)]; wc = Pdot[2048 + i * 8 + (g - 8)];
    }
    float part = 0.f;
#pragma unroll
    for (int t = 0; t < 7; t++) {
        int c = q + 4 * t;
        if (c < 25) {
            float4 a = prow4[c], b = psum4[c];
            part += a.x * b.x + a.y * b.y + a.z * b.z + a.w * b.w;
        }
    }
    part += __shfl_xor(part, 1, 64);
    part += __shfl_xor(part, 2, 64);
    float sg = sigmoidf_(part);
    float cr = (q == 0) ? sg * wr : 0.f;
    float cc = (q == 0) ? sg * wc : 0.f;
    for (int s = 4; s < 64; s <<= 1) { cr += __shfl_xor(cr, s, 64); cc += __shfl_xor(cc, s, 64); }
    if (lane == 0) {
        out[e] = cr + user_bias[u] + item_bias[i] + global_bias[0];
        out[20000 + e] = cc;
    }
}

// ---------------------------------------------------------------------------
extern "C" void kernel_launch(void* const* d_in, const int* in_sizes, int n_in,
                              void* d_out, int out_size, void* d_ws, size_t ws_size,
                              hipStream_t stream) {
    const int*   u_rev    = (const int*)d_in[0];
    const int*   i_rev    = (const int*)d_in[1];
    const int*   uid      = (const int*)d_in[2];
    const int*   iid      = (const int*)d_in[3];
    const float* emb      = (const float*)d_in[4];
    const float* conv_w   = (const float*)d_in[5];
    const float* conv_b   = (const float*)d_in[6];
    const float* fc_w_w   = (const float*)d_in[7];
    const float* fc_w_b   = (const float*)d_in[8];
    const float* fc_w2_w  = (const float*)d_in[9];
    const float* fc_w2_b  = (const float*)d_in[10];
    const float* h_r_w    = (const float*)d_in[11];
    const float* h_c_w    = (const float*)d_in[12];
    const float* user_b   = (const float*)d_in[13];
    const float* item_b   = (const float*)d_in[14];
    const float* global_b = (const float*)d_in[15];
    float* out = (float*)d_out;

    float*  ws    = (float*)d_ws;
    float*  Pbuf  = ws;                      // [409600]
    float*  Psum  = ws + 409600;             // [51200]
    float*  zdotb = ws + 460800;             // [4096]
    float*  Pdotb = ws + 464896;             // [4096]
    float*  Wt    = ws + 468992;             // [30000]
    float*  fc2t  = ws + 498992;             // [10000]
    ushort* wpack = (ushort*)(ws + 508992);  // [35840] bf16 (16B-aligned)
    int*    flagc = (int*)(ws + 526912);     // [1]
    int*    flist = (int*)(ws + 526916);     // [204800]

    hipLaunchKernelGGL(k_prep, dim3(497), dim3(256), 0, stream,
                       conv_w, fc_w2_w, Wt, fc2t, Psum, wpack, flagc);
    hipLaunchKernelGGL(k_branch, dim3(1366), dim3(192), 0, stream,
                       u_rev, i_rev, emb, wpack, conv_b, fc_w_w, fc_w_b,
                       fc_w2_b, fc2t, h_r_w, h_c_w,
                       Pbuf, Psum, zdotb, Pdotb, out + 40000, flagc, flist);
    hipLaunchKernelGGL(k_refine, dim3(256), dim3(256), 0, stream,
                       u_rev, i_rev, emb, Wt, conv_b, fc_w_w, fc_w_b, h_r_w,
                       flagc, flist, out + 40000, zdotb);
    hipLaunchKernelGGL(k_edge, dim3(5000), dim3(256), 0, stream,
                       uid, iid, Pbuf, Psum, zdotb, Pdotb,
                       user_b, item_b, global_b, out);
}

// Round 7
// 296.544 us; speedup vs baseline: 4.9341x; 4.9341x over previous
//
#include <hip/hip_runtime.h>
#include <math.h>

// Model: review-based recommender. ALL float tensors fp32.
// Shapes: VOCAB=20000, D=100, H=100, K=3, N_U=N_I=256, R=8, S=52, Sp=50, E=20000.
// Outputs (fp32, flat): pred_r[20000] @0, pred_c[20000] @20000,
//                       z_u[102400] @40000, z_i[102400] @142400.
//
// R7: conv on MFMA (r6-verified layouts). Fixes vs r6:
//  - k_branch: per-wave aggregated flag push (ballot + 1 atomic/wave) instead
//    of ~25k serialized single-cacheline atomics.
//  - k_refine: 4 items/wave, x broadcast via shfl regs (no serial dependent
//    loads), coalesced W reads amortized across items, unrolled.
//  - refine margin 1e-2 -> 5e-3 (est. max bf16 logit err ~2e-3).

typedef __attribute__((ext_vector_type(8))) short short8;
typedef __attribute__((ext_vector_type(4))) float f32x4;

__device__ __forceinline__ float sigmoidf_(float x) { return 1.f / (1.f + expf(-x)); }
__device__ __forceinline__ ushort f2b(float f) {
    union { float f; unsigned int i; } c; c.f = f;
    unsigned int x = c.i;
    return (ushort)((x + 0x7fffu + ((x >> 16) & 1u)) >> 16);
}

#define Z_MARGIN 5e-3f
#define FLAG_CAP 204800

// ---------------------------------------------------------------------------
// K0: prep. Wt[kk=300][h=100] fp32 (refine); fc2t[h][dd]; zero Psum;
// wpack bf16 B-frag layout (r6-verified); zero flag counter.
__global__ void k_prep(const float* __restrict__ conv_w, const float* __restrict__ fc_w2_w,
                       float* __restrict__ Wt, float* __restrict__ fc2t,
                       float* __restrict__ Psum, ushort* __restrict__ wpack,
                       int* __restrict__ flag_cnt) {
    int idx = blockIdx.x * 256 + threadIdx.x;
    if (idx < 30000) {
        int kk = idx / 100, h = idx - kk * 100;
        Wt[idx] = conv_w[h * 300 + kk];
    } else if (idx < 40000) {
        int j = idx - 30000;
        int h = j / 100, dd = j - h * 100;
        fc2t[j] = fc_w2_w[dd * 100 + h];
    } else if (idx < 91200) {
        Psum[idx - 40000] = 0.f;
    } else if (idx < 127040) {
        int j = idx - 91200;                   // [0, 35840)
        int frag = j >> 9, within = j & 511;
        int l = within >> 3, jj = within & 7;
        int kt = frag / 7, nt = frag % 7;
        int kk = kt * 32 + ((l >> 4) << 3) + jj;
        int h  = nt * 16 + (l & 15);
        ushort v = 0;
        if (kk < 300 && h < 100) v = f2b(conv_w[h * 300 + kk]);
        wpack[j] = v;
    } else if (idx == 127040) {
        *flag_cnt = 0;
    }
}

// ---------------------------------------------------------------------------
// K1: 192 threads = 3 waves; wave w owns instance gi = blockIdx*3 + w.
__global__ __launch_bounds__(192, 2)
void k_branch(const int* __restrict__ u_rev, const int* __restrict__ i_rev,
              const float* __restrict__ emb, const ushort* __restrict__ wpack,
              const float* __restrict__ conv_b, const float* __restrict__ fc_w_w,
              const float* __restrict__ fc_w_b, const float* __restrict__ fc_w2_b,
              const float* __restrict__ fc2t, const float* __restrict__ h_r_w,
              const float* __restrict__ h_c_w,
              float* __restrict__ Pbuf, float* __restrict__ Psum,
              float* __restrict__ zdot, float* __restrict__ Pdot,
              float* __restrict__ z_out, int* __restrict__ flag_cnt,
              int* __restrict__ flag_list) {
    __shared__ __align__(16) char smem[51392];
    ushort* embf = (ushort*)smem;                    // [3][6656] bf16 X (zero-padded)
    ushort* wbuf = (ushort*)(smem + 39936);          // [3584] one kt-chunk of B-frags
    int*    s_tok = (int*)(smem + 47104);            // [3][52]
    float*  s_max = (float*)(smem + 47728);          // [3][100]
    float*  s_z   = (float*)(smem + 48928);          // [3][52]
    float*  s_P   = (float*)(smem + 49552);          // [3][100]
    float*  s_lg  = (float*)(smem + 50752);          // [3][52] logits

    const int tid = threadIdx.x, lane = tid & 63, w = tid >> 6;
    const int gi = blockIdx.x * 3 + w;
    const bool valid = gi < 4096;
    const int branch = (gi >> 11) & 1, inst = gi & 2047;
    ushort* embw = embf + w * 6656;

    const uint4* wp4 = (const uint4*)wpack;
    uint4* wbuf4 = (uint4*)wbuf;
    uint4 st[3];
    {
#pragma unroll
        for (int k = 0; k < 3; k++) {
            int idx = tid + 192 * k;
            if (idx < 448) st[k] = wp4[idx];         // kt = 0
        }
    }

    if (valid) {
        const int* rev = branch ? i_rev : u_rev;
        if (lane < 52) s_tok[w * 52 + lane] = rev[inst * 52 + lane];
        const float4* emb4 = (const float4*)emb;
        for (int idx = lane; idx < 1300; idx += 64) {
            int s = idx / 25, c = idx - s * 25;
            float4 v = emb4[s_tok[w * 52 + s] * 25 + c];
            uint2 o;
            o.x = (unsigned)f2b(v.x) | ((unsigned)f2b(v.y) << 16);
            o.y = (unsigned)f2b(v.z) | ((unsigned)f2b(v.w) << 16);
            *(uint2*)(embw + idx * 4) = o;
        }
        for (int idx = 1300 + lane; idx < 1664; idx += 64) {
            uint2 o; o.x = 0u; o.y = 0u;
            *(uint2*)(embw + idx * 4) = o;
        }
    }

    {
#pragma unroll
        for (int k = 0; k < 3; k++) {
            int idx = tid + 192 * k;
            if (idx < 448) wbuf4[idx] = st[k];
        }
#pragma unroll
        for (int k = 0; k < 3; k++) {
            int idx = tid + 192 * k;
            if (idx < 448) st[k] = wp4[448 + idx];   // kt = 1
        }
    }
    __syncthreads();

    f32x4 acc[4][7];
#pragma unroll
    for (int mt = 0; mt < 4; mt++)
#pragma unroll
        for (int nt = 0; nt < 7; nt++) acc[mt][nt] = (f32x4){0.f, 0.f, 0.f, 0.f};

    const int col = lane & 15, quad = lane >> 4;

    for (int kt = 0; kt < 10; kt++) {
        if (valid) {
            union AU { short8 s8; uint2 u2[2]; } a[4];
            const int q8 = quad << 3;
#pragma unroll
            for (int mt = 0; mt < 4; mt++) {
                int e0 = (mt * 16 + col) * 100 + kt * 32 + q8;
                a[mt].u2[0] = *(const uint2*)(embw + e0);
                a[mt].u2[1] = *(const uint2*)(embw + e0 + 4);
            }
#pragma unroll
            for (int nt = 0; nt < 7; nt++) {
                union BU { short8 s8; uint4 u4; } b;
                b.u4 = wbuf4[nt * 64 + lane];
                acc[0][nt] = __builtin_amdgcn_mfma_f32_16x16x32_bf16(a[0].s8, b.s8, acc[0][nt], 0, 0, 0);
                acc[1][nt] = __builtin_amdgcn_mfma_f32_16x16x32_bf16(a[1].s8, b.s8, acc[1][nt], 0, 0, 0);
                acc[2][nt] = __builtin_amdgcn_mfma_f32_16x16x32_bf16(a[2].s8, b.s8, acc[2][nt], 0, 0, 0);
                acc[3][nt] = __builtin_amdgcn_mfma_f32_16x16x32_bf16(a[3].s8, b.s8, acc[3][nt], 0, 0, 0);
            }
        }
        __syncthreads();
        if (kt < 9) {
#pragma unroll
            for (int k = 0; k < 3; k++) {
                int idx = tid + 192 * k;
                if (idx < 448) wbuf4[idx] = st[k];
            }
            if (kt < 8) {
#pragma unroll
                for (int k = 0; k < 3; k++) {
                    int idx = tid + 192 * k;
                    if (idx < 448) st[k] = wp4[(kt + 2) * 448 + idx];
                }
            }
            __syncthreads();
        }
    }

    if (!valid) return;                              // no barriers below

    // --- epilogue. C/D layout: n=col, m-row = quad*4+j [m89/m91, r6-verified].
    float cb[7], fw[7], vmax[7];
#pragma unroll
    for (int nt = 0; nt < 7; nt++) {
        int h = nt * 16 + col;
        cb[nt] = (h < 100) ? conv_b[h] : 0.f;
        fw[nt] = (h < 100) ? fc_w_w[h] : 0.f;
        vmax[nt] = 0.f;
    }
    const float fcb = fc_w_b[0];

#pragma unroll
    for (int mt = 0; mt < 4; mt++) {
#pragma unroll
        for (int j = 0; j < 4; j++) {
            int p = mt * 16 + quad * 4 + j;
            bool pv = p < 50;
            float part = 0.f;
#pragma unroll
            for (int nt = 0; nt < 7; nt++) {
                float c = acc[mt][nt][j] + cb[nt];
                c = c > 0.f ? c : 0.f;
                part += c * fw[nt];
                if (pv) vmax[nt] = fmaxf(vmax[nt], c);
            }
            part += __shfl_xor(part, 1, 64);
            part += __shfl_xor(part, 2, 64);
            part += __shfl_xor(part, 4, 64);
            part += __shfl_xor(part, 8, 64);
            if (pv && col == 0) {
                float logit = part + fcb;
                float z = rintf(sigmoidf_(logit));
                s_z[w * 52 + p] = z;
                s_lg[w * 52 + p] = logit;
                z_out[branch * 102400 + inst * 50 + p] = z;
            }
        }
    }

    // aggregated flag push: one atomic per wave (same-wave LDS pattern as s_z)
    {
        float lg = 1e9f;
        if (lane < 50) lg = s_lg[w * 52 + lane];
        unsigned long long mb = __ballot(fabsf(lg) < Z_MARGIN);
        int cnt = __popcll(mb);
        int base = 0;
        if (lane == 0 && cnt) base = atomicAdd(flag_cnt, cnt);
        base = __shfl(base, 0, 64);
        if (fabsf(lg) < Z_MARGIN) {
            int rank = __popcll(mb & ((1ull << lane) - 1ull));
            int k = base + rank;
            if (k < FLAG_CAP) flag_list[k] = gi * 50 + lane;
        }
    }

#pragma unroll
    for (int nt = 0; nt < 7; nt++) {
        float m = vmax[nt];
        m = fmaxf(m, __shfl_xor(m, 16, 64));
        m = fmaxf(m, __shfl_xor(m, 32, 64));
        int h = nt * 16 + col;
        if (quad == 0 && h < 100) s_max[w * 100 + h] = m;
    }

    if (lane < 50) {
        float a0 = fc_w2_b[lane], a1 = fc_w2_b[lane + 50];
        for (int h = 0; h < 100; h++) {
            float mx = s_max[w * 100 + h];
            a0 += mx * fc2t[h * 100 + lane];
            a1 += mx * fc2t[h * 100 + lane + 50];
        }
        Pbuf[gi * 100 + lane] = a0;
        Pbuf[gi * 100 + lane + 50] = a1;
        s_P[w * 100 + lane] = a0;
        s_P[w * 100 + lane + 50] = a1;
        atomicAdd(&Psum[(branch * 256 + (inst >> 3)) * 100 + lane], a0);
        atomicAdd(&Psum[(branch * 256 + (inst >> 3)) * 100 + lane + 50], a1);
    }

    {
        float v = (lane < 50) ? s_z[w * 52 + lane] * h_r_w[branch * 50 + lane] : 0.f;
        for (int s = 1; s < 64; s <<= 1) v += __shfl_xor(v, s, 64);
        if (lane == 0) zdot[gi] = v;
        float u = 0.f;
        if (lane < 50) u = s_P[w * 100 + lane] * h_c_w[branch * 100 + lane]
                         + s_P[w * 100 + lane + 50] * h_c_w[branch * 100 + lane + 50];
        for (int s = 1; s < 64; s <<= 1) u += __shfl_xor(u, s, 64);
        if (lane == 0) Pdot[gi] = u;
    }
}

// ---------------------------------------------------------------------------
// K2: exact fp32 recompute of flagged z-logits; 4 items per wave jointly
// (W loads amortized), x broadcast from regs via shfl. Patches z_out + zdot.
__launch_bounds__(256)
__global__ void k_refine(const int* __restrict__ u_rev, const int* __restrict__ i_rev,
                         const float* __restrict__ emb, const float* __restrict__ Wt,
                         const float* __restrict__ conv_b, const float* __restrict__ fc_w_w,
                         const float* __restrict__ fc_w_b, const float* __restrict__ h_r_w,
                         const int* __restrict__ flag_cnt, const int* __restrict__ flag_list,
                         float* __restrict__ z_out, float* __restrict__ zdot) {
    int n = *flag_cnt; if (n > FLAG_CAP) n = FLAG_CAP;
    const int lane = threadIdx.x & 63;
    const int wid = (blockIdx.x * 256 + threadIdx.x) >> 6;
    const int nw = gridDim.x * 4;
    const bool hv = lane < 50;
    const float cb0 = hv ? conv_b[lane] : 0.f;
    const float cb1 = hv ? conv_b[lane + 50] : 0.f;
    const float fw0 = hv ? fc_w_w[lane] : 0.f;
    const float fw1 = hv ? fc_w_w[lane + 50] : 0.f;
    const float fcb = fc_w_b[0];

    for (int e0 = wid * 4; e0 < n; e0 += nw * 4) {
        int gi[4], pos[4];
        bool iv[4];
        float xr[4][5];
#pragma unroll
        for (int m = 0; m < 4; m++) {
            int e = e0 + m;
            iv[m] = e < n;
            int code = iv[m] ? flag_list[e] : 0;
            gi[m] = code / 50; pos[m] = code - gi[m] * 50;
            const int* rev = (gi[m] >> 11) ? i_rev : u_rev;
            int tb = (gi[m] & 2047) * 52 + pos[m];
            int t0 = rev[tb], t1 = rev[tb + 1], t2 = rev[tb + 2];
#pragma unroll
            for (int s = 0; s < 5; s++) {
                int k = s * 64 + lane;
                float v = 0.f;
                if (k < 300) {
                    int r = k / 100, dd = k - r * 100;
                    int t = (r == 0) ? t0 : ((r == 1) ? t1 : t2);
                    v = emb[t * 100 + dd];
                }
                xr[m][s] = v;
            }
        }
        float c0[4], c1[4];
#pragma unroll
        for (int m = 0; m < 4; m++) { c0[m] = cb0; c1[m] = cb1; }
#pragma unroll
        for (int s = 0; s < 5; s++) {
            const int dmax = (s < 4) ? 64 : 44;
#pragma unroll 4
            for (int d2 = 0; d2 < dmax; d2++) {
                int d = s * 64 + d2;
                float w0 = hv ? Wt[d * 100 + lane] : 0.f;
                float w1 = hv ? Wt[d * 100 + lane + 50] : 0.f;
#pragma unroll
                for (int m = 0; m < 4; m++) {
                    float x = __shfl(xr[m][s], d2, 64);
                    c0[m] += x * w0;
                    c1[m] += x * w1;
                }
            }
        }
#pragma unroll
        for (int m = 0; m < 4; m++) {
            float v = fmaxf(c0[m], 0.f) * fw0 + fmaxf(c1[m], 0.f) * fw1;
            for (int s = 1; s < 64; s <<= 1) v += __shfl_xor(v, s, 64);
            if (lane == 0 && iv[m]) {
                int branch = gi[m] >> 11, inst = gi[m] & 2047;
                float z = rintf(sigmoidf_(v + fcb));
                float old = z_out[branch * 102400 + inst * 50 + pos[m]];
                if (z != old) {
                    z_out[branch * 102400 + inst * 50 + pos[m]] = z;
                    atomicAdd(&zdot[gi[m]], (z - old) * h_r_w[branch * 50 + pos[m]]);
                }
            }
        }
    }
}

// ---------------------------------------------------------------------------
// K3: per-edge (verified r5/r6).
__launch_bounds__(256)
__global__ void k_edge(const int* __restrict__ uid, const int* __restrict__ iid,
                       const float* __restrict__ Pbuf, const float* __restrict__ Psum,
                       const float* __restrict__ zdot, const float* __restrict__ Pdot,
                       const float* __restrict__ user_bias, const float* __restrict__ item_bias,
                       const float* __restrict__ global_bias, float* __restrict__ out) {
    int wave = threadIdx.x >> 6, lane = threadIdx.x & 63;
    int e = blockIdx.x * 4 + wave;
    int u = uid[e], i = iid[e];
    int g = lane >> 2, q = lane & 3;
    const float4* prow4; const float4* psum4; float wr, wc;
    if (g < 8) {
        prow4 = (const float4*)(Pbuf + (u * 8 + g) * 100);
        psum4 = (const float4*)(Psum + 25600 + i * 100);
        wr = zdot[u * 8 + g]; wc = Pdot[u * 8 + g];
    } else {
        prow4 = (const float4*)(Pbuf + (2048 + i * 8 + (g - 8)) * 100);
        psum4 = (const float4*)(Psum + u * 100);
        wr = zdot[2048 + i * 8 + (g - 8)]; wc = Pdot[2048 + i * 8 + (g - 8)];
    }
    float part = 0.f;
#pragma unroll
    for (int t = 0; t < 7; t++) {
        int c = q + 4 * t;
        if (c < 25) {
            float4 a = prow4[c], b = psum4[c];
            part += a.x * b.x + a.y * b.y + a.z * b.z + a.w * b.w;
        }
    }
    part += __shfl_xor(part, 1, 64);
    part += __shfl_xor(part, 2, 64);
    float sg = sigmoidf_(part);
    float cr = (q == 0) ? sg * wr : 0.f;
    float cc = (q == 0) ? sg * wc : 0.f;
    for (int s = 4; s < 64; s <<= 1) { cr += __shfl_xor(cr, s, 64); cc += __shfl_xor(cc, s, 64); }
    if (lane == 0) {
        out[e] = cr + user_bias[u] + item_bias[i] + global_bias[0];
        out[20000 + e] = cc;
    }
}

// ---------------------------------------------------------------------------
extern "C" void kernel_launch(void* const* d_in, const int* in_sizes, int n_in,
                              void* d_out, int out_size, void* d_ws, size_t ws_size,
                              hipStream_t stream) {
    const int*   u_rev    = (const int*)d_in[0];
    const int*   i_rev    = (const int*)d_in[1];
    const int*   uid      = (const int*)d_in[2];
    const int*   iid      = (const int*)d_in[3];
    const float* emb      = (const float*)d_in[4];
    const float* conv_w   = (const float*)d_in[5];
    const float* conv_b   = (const float*)d_in[6];
    const float* fc_w_w   = (const float*)d_in[7];
    const float* fc_w_b   = (const float*)d_in[8];
    const float* fc_w2_w  = (const float*)d_in[9];
    const float* fc_w2_b  = (const float*)d_in[10];
    const float* h_r_w    = (const float*)d_in[11];
    const float* h_c_w    = (const float*)d_in[12];
    const float* user_b   = (const float*)d_in[13];
    const float* item_b   = (const float*)d_in[14];
    const float* global_b = (const float*)d_in[15];
    float* out = (float*)d_out;

    float*  ws    = (float*)d_ws;
    float*  Pbuf  = ws;                      // [409600]
    float*  Psum  = ws + 409600;             // [51200]
    float*  zdotb = ws + 460800;             // [4096]
    float*  Pdotb = ws + 464896;             // [4096]
    float*  Wt    = ws + 468992;             // [30000]
    float*  fc2t  = ws + 498992;             // [10000]
    ushort* wpack = (ushort*)(ws + 508992);  // [35840] bf16 (16B-aligned)
    int*    flagc = (int*)(ws + 526912);     // [1]
    int*    flist = (int*)(ws + 526916);     // [204800]

    hipLaunchKernelGGL(k_prep, dim3(497), dim3(256), 0, stream,
                       conv_w, fc_w2_w, Wt, fc2t, Psum, wpack, flagc);
    hipLaunchKernelGGL(k_branch, dim3(1366), dim3(192), 0, stream,
                       u_rev, i_rev, emb, wpack, conv_b, fc_w_w, fc_w_b,
                       fc_w2_b, fc2t, h_r_w, h_c_w,
                       Pbuf, Psum, zdotb, Pdotb, out + 40000, flagc, flist);
    hipLaunchKernelGGL(k_refine, dim3(512), dim3(256), 0, stream,
                       u_rev, i_rev, emb, Wt, conv_b, fc_w_w, fc_w_b, h_r_w,
                       flagc, flist, out + 40000, zdotb);
    hipLaunchKernelGGL(k_edge, dim3(5000), dim3(256), 0, stream,
                       uid, iid, Pbuf, Psum, zdotb, Pdotb,
                       user_b, item_b, global_b, out);
}

// Round 8
// 267.950 us; speedup vs baseline: 5.4607x; 1.1067x over previous
//
#include <hip/hip_runtime.h>
#include <math.h>

// Model: review-based recommender. ALL float tensors fp32.
// Shapes: VOCAB=20000, D=100, H=100, K=3, N_U=N_I=256, R=8, S=52, Sp=50, E=20000.
// Outputs (fp32, flat): pred_r[20000] @0, pred_c[20000] @20000,
//                       z_u[102400] @40000, z_i[102400] @142400.
//
// R8: split-precision conv: X = Xhi + Xlo (bf16 pair packed in uint32 LDS),
// W = RNE bf16 (r7-verified wpack). 2 MFMA per tile -> conv error is
// W-rounding-only (max logit err ~6e-4) -> refine margin 2e-3, n ~6k.
// Latency fixes: gather batched 5-deep; P-matvec loop chunk-unrolled (the
// r7 rolled loops paid ~full L2 latency per iteration).

typedef __attribute__((ext_vector_type(8))) short short8;
typedef __attribute__((ext_vector_type(4))) float f32x4;

__device__ __forceinline__ float sigmoidf_(float x) { return 1.f / (1.f + expf(-x)); }
__device__ __forceinline__ ushort f2b(float f) {
    union { float f; unsigned int i; } c; c.f = f;
    unsigned int x = c.i;
    return (ushort)((x + 0x7fffu + ((x >> 16) & 1u)) >> 16);
}
// pack fp32 -> (hi bf16 trunc | lo bf16 RNE of residual); hi+lo represents x
// to ~2^-16 relative.
__device__ __forceinline__ unsigned int pack_hl(float x) {
    union { float f; unsigned int i; } c; c.f = x;
    unsigned int hi = c.i & 0xFFFF0000u;
    union { float f; unsigned int i; } h; h.i = hi;
    return hi | (unsigned int)f2b(x - h.f);
}

#define Z_MARGIN 2e-3f
#define FLAG_CAP 204800

// ---------------------------------------------------------------------------
// K0: prep (identical to r7-verified). Wt[kk][h] fp32; fc2t[h][dd]; zero Psum;
// wpack bf16 B-frag layout (RNE); zero flag counter.
__global__ void k_prep(const float* __restrict__ conv_w, const float* __restrict__ fc_w2_w,
                       float* __restrict__ Wt, float* __restrict__ fc2t,
                       float* __restrict__ Psum, ushort* __restrict__ wpack,
                       int* __restrict__ flag_cnt) {
    int idx = blockIdx.x * 256 + threadIdx.x;
    if (idx < 30000) {
        int kk = idx / 100, h = idx - kk * 100;
        Wt[idx] = conv_w[h * 300 + kk];
    } else if (idx < 40000) {
        int j = idx - 30000;
        int h = j / 100, dd = j - h * 100;
        fc2t[j] = fc_w2_w[dd * 100 + h];
    } else if (idx < 91200) {
        Psum[idx - 40000] = 0.f;
    } else if (idx < 127040) {
        int j = idx - 91200;                   // [0, 35840)
        int frag = j >> 9, within = j & 511;
        int l = within >> 3, jj = within & 7;
        int kt = frag / 7, nt = frag % 7;
        int kk = kt * 32 + ((l >> 4) << 3) + jj;
        int h  = nt * 16 + (l & 15);
        ushort v = 0;
        if (kk < 300 && h < 100) v = f2b(conv_w[h * 300 + kk]);
        wpack[j] = v;
    } else if (idx == 127040) {
        *flag_cnt = 0;
    }
}

// ---------------------------------------------------------------------------
// K1: 192 threads = 3 waves; wave w owns instance gi = blockIdx*3 + w.
__global__ __launch_bounds__(192, 2)
void k_branch(const int* __restrict__ u_rev, const int* __restrict__ i_rev,
              const float* __restrict__ emb, const ushort* __restrict__ wpack,
              const float* __restrict__ conv_b, const float* __restrict__ fc_w_w,
              const float* __restrict__ fc_w_b, const float* __restrict__ fc_w2_b,
              const float* __restrict__ fc2t, const float* __restrict__ h_r_w,
              const float* __restrict__ h_c_w,
              float* __restrict__ Pbuf, float* __restrict__ Psum,
              float* __restrict__ zdot, float* __restrict__ Pdot,
              float* __restrict__ z_out, int* __restrict__ flag_cnt,
              int* __restrict__ flag_list) {
    __shared__ __align__(16) char smem[74080];
    unsigned int* s_x = (unsigned int*)smem;         // [3][5220] packed hi|lo X
    ushort* wbuf  = (ushort*)(smem + 62640);         // [3584] one kt-chunk B-frags
    int*    s_tok = (int*)(smem + 69808);            // [3][52]
    float*  s_max = (float*)(smem + 70432);          // [3][100]
    float*  s_z   = (float*)(smem + 71632);          // [3][52]
    float*  s_P   = (float*)(smem + 72256);          // [3][100]
    float*  s_lg  = (float*)(smem + 73456);          // [3][52]

    const int tid = threadIdx.x, lane = tid & 63, w = tid >> 6;
    const int gi = blockIdx.x * 3 + w;
    const bool valid = gi < 4096;
    const int branch = (gi >> 11) & 1, inst = gi & 2047;
    unsigned int* xw = s_x + w * 5220;

    const uint4* wp4 = (const uint4*)wpack;
    uint4* wbuf4 = (uint4*)wbuf;
    uint4 st[3];
#pragma unroll
    for (int k = 0; k < 3; k++) {
        int idx = tid + 192 * k;
        if (idx < 448) st[k] = wp4[idx];             // kt = 0
    }

    // --- gather: tokens, then emb rows fp32 -> packed hi|lo LDS (batched 5)
    if (valid) {
        const int* rev = branch ? i_rev : u_rev;
        if (lane < 52) s_tok[w * 52 + lane] = rev[inst * 52 + lane];
        const float4* emb4 = (const float4*)emb;
        for (int base = 0; base < 1300; base += 320) {
            float4 v[5];
#pragma unroll
            for (int k = 0; k < 5; k++) {
                int idx = base + k * 64 + lane;
                if (idx < 1300) {
                    int s = idx / 25, c = idx - s * 25;
                    v[k] = emb4[s_tok[w * 52 + s] * 25 + c];
                }
            }
#pragma unroll
            for (int k = 0; k < 5; k++) {
                int idx = base + k * 64 + lane;
                if (idx < 1300) {
                    uint4 o;
                    o.x = pack_hl(v[k].x); o.y = pack_hl(v[k].y);
                    o.z = pack_hl(v[k].z); o.w = pack_hl(v[k].w);
                    *(uint4*)(xw + idx * 4) = o;
                }
            }
        }
        if (lane < 20) xw[5200 + lane] = 0u;         // zero pad (kk>=300 zone)
    }

    // write kt=0 chunk, preload kt=1
    {
#pragma unroll
        for (int k = 0; k < 3; k++) {
            int idx = tid + 192 * k;
            if (idx < 448) wbuf4[idx] = st[k];
        }
#pragma unroll
        for (int k = 0; k < 3; k++) {
            int idx = tid + 192 * k;
            if (idx < 448) st[k] = wp4[448 + idx];
        }
    }
    __syncthreads();

    f32x4 acc[4][7];
#pragma unroll
    for (int mt = 0; mt < 4; mt++)
#pragma unroll
        for (int nt = 0; nt < 7; nt++) acc[mt][nt] = (f32x4){0.f, 0.f, 0.f, 0.f};

    const int col = lane & 15, quad = lane >> 4;

    for (int kt = 0; kt < 10; kt++) {
        if (valid) {
            union AU { short8 s8; uint4 u; } ah[4], al[4];
            const int q8 = quad << 3;
#pragma unroll
            for (int mt = 0; mt < 4; mt++) {
                int e0 = (mt * 16 + col) * 100 + kt * 32 + q8;
                uint4 xa = *(const uint4*)(xw + e0);
                uint4 xb = *(const uint4*)(xw + e0 + 4);
                ah[mt].u.x = (xa.x >> 16) | (xa.y & 0xFFFF0000u);
                ah[mt].u.y = (xa.z >> 16) | (xa.w & 0xFFFF0000u);
                ah[mt].u.z = (xb.x >> 16) | (xb.y & 0xFFFF0000u);
                ah[mt].u.w = (xb.z >> 16) | (xb.w & 0xFFFF0000u);
                al[mt].u.x = (xa.x & 0xFFFFu) | (xa.y << 16);
                al[mt].u.y = (xa.z & 0xFFFFu) | (xa.w << 16);
                al[mt].u.z = (xb.x & 0xFFFFu) | (xb.y << 16);
                al[mt].u.w = (xb.z & 0xFFFFu) | (xb.w << 16);
            }
#pragma unroll
            for (int nt = 0; nt < 7; nt++) {
                union BU { short8 s8; uint4 u4; } b;
                b.u4 = wbuf4[nt * 64 + lane];
#pragma unroll
                for (int mt = 0; mt < 4; mt++) {
                    acc[mt][nt] = __builtin_amdgcn_mfma_f32_16x16x32_bf16(al[mt].s8, b.s8, acc[mt][nt], 0, 0, 0);
                    acc[mt][nt] = __builtin_amdgcn_mfma_f32_16x16x32_bf16(ah[mt].s8, b.s8, acc[mt][nt], 0, 0, 0);
                }
            }
        }
        __syncthreads();
        if (kt < 9) {
#pragma unroll
            for (int k = 0; k < 3; k++) {
                int idx = tid + 192 * k;
                if (idx < 448) wbuf4[idx] = st[k];
            }
            if (kt < 8) {
#pragma unroll
                for (int k = 0; k < 3; k++) {
                    int idx = tid + 192 * k;
                    if (idx < 448) st[k] = wp4[(kt + 2) * 448 + idx];
                }
            }
            __syncthreads();
        }
    }

    if (!valid) return;                              // no barriers below

    // --- epilogue. C/D layout: n=col, m-row = quad*4+j [r6/r7-verified].
    float cb[7], fw[7], vmax[7];
#pragma unroll
    for (int nt = 0; nt < 7; nt++) {
        int h = nt * 16 + col;
        cb[nt] = (h < 100) ? conv_b[h] : 0.f;
        fw[nt] = (h < 100) ? fc_w_w[h] : 0.f;
        vmax[nt] = 0.f;
    }
    const float fcb = fc_w_b[0];

#pragma unroll
    for (int mt = 0; mt < 4; mt++) {
#pragma unroll
        for (int j = 0; j < 4; j++) {
            int p = mt * 16 + quad * 4 + j;
            bool pv = p < 50;
            float part = 0.f;
#pragma unroll
            for (int nt = 0; nt < 7; nt++) {
                float c = acc[mt][nt][j] + cb[nt];
                c = c > 0.f ? c : 0.f;
                part += c * fw[nt];
                if (pv) vmax[nt] = fmaxf(vmax[nt], c);
            }
            part += __shfl_xor(part, 1, 64);
            part += __shfl_xor(part, 2, 64);
            part += __shfl_xor(part, 4, 64);
            part += __shfl_xor(part, 8, 64);
            if (pv && col == 0) {
                float logit = part + fcb;
                float z = rintf(sigmoidf_(logit));
                s_z[w * 52 + p] = z;
                s_lg[w * 52 + p] = logit;
                z_out[branch * 102400 + inst * 50 + p] = z;
            }
        }
    }

    // aggregated flag push (r7-verified): one atomic per wave
    {
        float lg = 1e9f;
        if (lane < 50) lg = s_lg[w * 52 + lane];
        unsigned long long mb = __ballot(fabsf(lg) < Z_MARGIN);
        int cnt = __popcll(mb);
        int base = 0;
        if (lane == 0 && cnt) base = atomicAdd(flag_cnt, cnt);
        base = __shfl(base, 0, 64);
        if (fabsf(lg) < Z_MARGIN) {
            int rank = __popcll(mb & ((1ull << lane) - 1ull));
            int k = base + rank;
            if (k < FLAG_CAP) flag_list[k] = gi * 50 + lane;
        }
    }

#pragma unroll
    for (int nt = 0; nt < 7; nt++) {
        float m = vmax[nt];
        m = fmaxf(m, __shfl_xor(m, 16, 64));
        m = fmaxf(m, __shfl_xor(m, 32, 64));
        int h = nt * 16 + col;
        if (quad == 0 && h < 100) s_max[w * 100 + h] = m;
    }

    // P matvec: chunk-unrolled so loads pipeline (r7 rolled loop = 100x L2 lat)
    if (lane < 50) {
        float a0 = fc_w2_b[lane], a1 = fc_w2_b[lane + 50];
        for (int h0 = 0; h0 < 100; h0 += 10) {
            float w0[10], w1[10], mx[10];
#pragma unroll
            for (int t = 0; t < 10; t++) {
                w0[t] = fc2t[(h0 + t) * 100 + lane];
                w1[t] = fc2t[(h0 + t) * 100 + lane + 50];
                mx[t] = s_max[w * 100 + h0 + t];
            }
#pragma unroll
            for (int t = 0; t < 10; t++) { a0 += mx[t] * w0[t]; a1 += mx[t] * w1[t]; }
        }
        Pbuf[gi * 100 + lane] = a0;
        Pbuf[gi * 100 + lane + 50] = a1;
        s_P[w * 100 + lane] = a0;
        s_P[w * 100 + lane + 50] = a1;
        atomicAdd(&Psum[(branch * 256 + (inst >> 3)) * 100 + lane], a0);
        atomicAdd(&Psum[(branch * 256 + (inst >> 3)) * 100 + lane + 50], a1);
    }

    {
        float v = (lane < 50) ? s_z[w * 52 + lane] * h_r_w[branch * 50 + lane] : 0.f;
        for (int s = 1; s < 64; s <<= 1) v += __shfl_xor(v, s, 64);
        if (lane == 0) zdot[gi] = v;
        float u = 0.f;
        if (lane < 50) u = s_P[w * 100 + lane] * h_c_w[branch * 100 + lane]
                         + s_P[w * 100 + lane + 50] * h_c_w[branch * 100 + lane + 50];
        for (int s = 1; s < 64; s <<= 1) u += __shfl_xor(u, s, 64);
        if (lane == 0) Pdot[gi] = u;
    }
}

// ---------------------------------------------------------------------------
// K2: exact fp32 recompute of flagged z-logits (r7-verified structure).
__launch_bounds__(256)
__global__ void k_refine(const int* __restrict__ u_rev, const int* __restrict__ i_rev,
                         const float* __restrict__ emb, const float* __restrict__ Wt,
                         const float* __restrict__ conv_b, const float* __restrict__ fc_w_w,
                         const float* __restrict__ fc_w_b, const float* __restrict__ h_r_w,
                         const int* __restrict__ flag_cnt, const int* __restrict__ flag_list,
                         float* __restrict__ z_out, float* __restrict__ zdot) {
    int n = *flag_cnt; if (n > FLAG_CAP) n = FLAG_CAP;
    const int lane = threadIdx.x & 63;
    const int wid = (blockIdx.x * 256 + threadIdx.x) >> 6;
    const int nw = gridDim.x * 4;
    const bool hv = lane < 50;
    const float cb0 = hv ? conv_b[lane] : 0.f;
    const float cb1 = hv ? conv_b[lane + 50] : 0.f;
    const float fw0 = hv ? fc_w_w[lane] : 0.f;
    const float fw1 = hv ? fc_w_w[lane + 50] : 0.f;
    const float fcb = fc_w_b[0];

    for (int e0 = wid * 4; e0 < n; e0 += nw * 4) {
        int gi[4], pos[4];
        bool iv[4];
        float xr[4][5];
#pragma unroll
        for (int m = 0; m < 4; m++) {
            int e = e0 + m;
            iv[m] = e < n;
            int code = iv[m] ? flag_list[e] : 0;
            gi[m] = code / 50; pos[m] = code - gi[m] * 50;
            const int* rev = (gi[m] >> 11) ? i_rev : u_rev;
            int tb = (gi[m] & 2047) * 52 + pos[m];
            int t0 = rev[tb], t1 = rev[tb + 1], t2 = rev[tb + 2];
#pragma unroll
            for (int s = 0; s < 5; s++) {
                int k = s * 64 + lane;
                float v = 0.f;
                if (k < 300) {
                    int r = k / 100, dd = k - r * 100;
                    int t = (r == 0) ? t0 : ((r == 1) ? t1 : t2);
                    v = emb[t * 100 + dd];
                }
                xr[m][s] = v;
            }
        }
        float c0[4], c1[4];
#pragma unroll
        for (int m = 0; m < 4; m++) { c0[m] = cb0; c1[m] = cb1; }
#pragma unroll
        for (int s = 0; s < 5; s++) {
            const int dmax = (s < 4) ? 64 : 44;
#pragma unroll 4
            for (int d2 = 0; d2 < dmax; d2++) {
                int d = s * 64 + d2;
                float w0 = hv ? Wt[d * 100 + lane] : 0.f;
                float w1 = hv ? Wt[d * 100 + lane + 50] : 0.f;
#pragma unroll
                for (int m = 0; m < 4; m++) {
                    float x = __shfl(xr[m][s], d2, 64);
                    c0[m] += x * w0;
                    c1[m] += x * w1;
                }
            }
        }
#pragma unroll
        for (int m = 0; m < 4; m++) {
            float v = fmaxf(c0[m], 0.f) * fw0 + fmaxf(c1[m], 0.f) * fw1;
            for (int s = 1; s < 64; s <<= 1) v += __shfl_xor(v, s, 64);
            if (lane == 0 && iv[m]) {
                int branch = gi[m] >> 11, inst = gi[m] & 2047;
                float z = rintf(sigmoidf_(v + fcb));
                float old = z_out[branch * 102400 + inst * 50 + pos[m]];
                if (z != old) {
                    z_out[branch * 102400 + inst * 50 + pos[m]] = z;
                    atomicAdd(&zdot[gi[m]], (z - old) * h_r_w[branch * 50 + pos[m]]);
                }
            }
        }
    }
}

// ---------------------------------------------------------------------------
// K3: per-edge (verified r5-r7).
__launch_bounds__(256)
__global__ void k_edge(const int* __restrict__ uid, const int* __restrict__ iid,
                       const float* __restrict__ Pbuf, const float* __restrict__ Psum,
                       const float* __restrict__ zdot, const float* __restrict__ Pdot,
                       const float* __restrict__ user_bias, const float* __restrict__ item_bias,
                       const float* __restrict__ global_bias, float* __restrict__ out) {
    int wave = threadIdx.x >> 6, lane = threadIdx.x & 63;
    int e = blockIdx.x * 4 + wave;
    int u = uid[e], i = iid[e];
    int g = lane >> 2, q = lane & 3;
    const float4* prow4; const float4* psum4; float wr, wc;
    if (g < 8) {
        prow4 = (const float4*)(Pbuf + (u * 8 + g) * 100);
        psum4 = (const float4*)(Psum + 25600 + i * 100);
        wr = zdot[u * 8 + g]; wc = Pdot[u * 8 + g];
    } else {
        prow4 = (const float4*)(Pbuf + (2048 + i * 8 + (g - 8)) * 100);
        psum4 = (const float4*)(Psum + u * 100);
        wr = zdot[2048 + i * 8 + (g - 8)]; wc = Pdot[2048 + i * 8 + (g - 8)];
    }
    float part = 0.f;
#pragma unroll
    for (int t = 0; t < 7; t++) {
        int c = q + 4 * t;
        if (c < 25) {
            float4 a = prow4[c], b = psum4[c];
            part += a.x * b.x + a.y * b.y + a.z * b.z + a.w * b.w;
        }
    }
    part += __shfl_xor(part, 1, 64);
    part += __shfl_xor(part, 2, 64);
    float sg = sigmoidf_(part);
    float cr = (q == 0) ? sg * wr : 0.f;
    float cc = (q == 0) ? sg * wc : 0.f;
    for (int s = 4; s < 64; s <<= 1) { cr += __shfl_xor(cr, s, 64); cc += __shfl_xor(cc, s, 64); }
    if (lane == 0) {
        out[e] = cr + user_bias[u] + item_bias[i] + global_bias[0];
        out[20000 + e] = cc;
    }
}

// ---------------------------------------------------------------------------
extern "C" void kernel_launch(void* const* d_in, const int* in_sizes, int n_in,
                              void* d_out, int out_size, void* d_ws, size_t ws_size,
                              hipStream_t stream) {
    const int*   u_rev    = (const int*)d_in[0];
    const int*   i_rev    = (const int*)d_in[1];
    const int*   uid      = (const int*)d_in[2];
    const int*   iid      = (const int*)d_in[3];
    const float* emb      = (const float*)d_in[4];
    const float* conv_w   = (const float*)d_in[5];
    const float* conv_b   = (const float*)d_in[6];
    const float* fc_w_w   = (const float*)d_in[7];
    const float* fc_w_b   = (const float*)d_in[8];
    const float* fc_w2_w  = (const float*)d_in[9];
    const float* fc_w2_b  = (const float*)d_in[10];
    const float* h_r_w    = (const float*)d_in[11];
    const float* h_c_w    = (const float*)d_in[12];
    const float* user_b   = (const float*)d_in[13];
    const float* item_b   = (const float*)d_in[14];
    const float* global_b = (const float*)d_in[15];
    float* out = (float*)d_out;

    float*  ws    = (float*)d_ws;
    float*  Pbuf  = ws;                      // [409600]
    float*  Psum  = ws + 409600;             // [51200]
    float*  zdotb = ws + 460800;             // [4096]
    float*  Pdotb = ws + 464896;             // [4096]
    float*  Wt    = ws + 468992;             // [30000]
    float*  fc2t  = ws + 498992;             // [10000]
    ushort* wpack = (ushort*)(ws + 508992);  // [35840] bf16
    int*    flagc = (int*)(ws + 526912);     // [1]
    int*    flist = (int*)(ws + 526916);     // [204800]

    hipLaunchKernelGGL(k_prep, dim3(497), dim3(256), 0, stream,
                       conv_w, fc_w2_w, Wt, fc2t, Psum, wpack, flagc);
    hipLaunchKernelGGL(k_branch, dim3(1366), dim3(192), 0, stream,
                       u_rev, i_rev, emb, wpack, conv_b, fc_w_w, fc_w_b,
                       fc_w2_b, fc2t, h_r_w, h_c_w,
                       Pbuf, Psum, zdotb, Pdotb, out + 40000, flagc, flist);
    hipLaunchKernelGGL(k_refine, dim3(512), dim3(256), 0, stream,
                       u_rev, i_rev, emb, Wt, conv_b, fc_w_w, fc_w_b, h_r_w,
                       flagc, flist, out + 40000, zdotb);
    hipLaunchKernelGGL(k_edge, dim3(5000), dim3(256), 0, stream,
                       uid, iid, Pbuf, Psum, zdotb, Pdotb,
                       user_b, item_b, global_b, out);
}

// Round 9
// 211.634 us; speedup vs baseline: 6.9138x; 1.2661x over previous
//
#include <hip/hip_runtime.h>
#include <math.h>

// Model: review-based recommender. ALL float tensors fp32.
// Shapes: VOCAB=20000, D=100, H=100, K=3, N_U=N_I=256, R=8, S=52, Sp=50, E=20000.
// Outputs (fp32, flat): pred_r[20000] @0, pred_c[20000] @20000,
//                       z_u[102400] @40000, z_i[102400] @142400.
//
// R9: k_branch was HBM-gather latency-bound (hbm_bytes/dur == measured BW,
// 6 waves/CU). Restructure: 1 instance per 256-thr block, mt-split over 4
// waves -> 37KB LDS, 4 blk/CU, 16 waves/CU, 2.7x in-flight gather bytes.
// Split-precision X (hi|lo bf16 packed u32) vs RNE-bf16 W as r8 (verified).

typedef __attribute__((ext_vector_type(8))) short short8;
typedef __attribute__((ext_vector_type(4))) float f32x4;

__device__ __forceinline__ float sigmoidf_(float x) { return 1.f / (1.f + expf(-x)); }
__device__ __forceinline__ ushort f2b(float f) {
    union { float f; unsigned int i; } c; c.f = f;
    unsigned int x = c.i;
    return (ushort)((x + 0x7fffu + ((x >> 16) & 1u)) >> 16);
}
__device__ __forceinline__ unsigned int pack_hl(float x) {
    union { float f; unsigned int i; } c; c.f = x;
    unsigned int hi = c.i & 0xFFFF0000u;
    union { float f; unsigned int i; } h; h.i = hi;
    return hi | (unsigned int)f2b(x - h.f);
}

#define Z_MARGIN 2e-3f
#define FLAG_CAP 204800

// ---------------------------------------------------------------------------
// K0: prep (r7/r8-verified): Wt[kk][h] fp32; fc2t[h][dd]; zero Psum;
// wpack bf16 B-frag layout (RNE); zero flag counter.
__global__ void k_prep(const float* __restrict__ conv_w, const float* __restrict__ fc_w2_w,
                       float* __restrict__ Wt, float* __restrict__ fc2t,
                       float* __restrict__ Psum, ushort* __restrict__ wpack,
                       int* __restrict__ flag_cnt) {
    int idx = blockIdx.x * 256 + threadIdx.x;
    if (idx < 30000) {
        int kk = idx / 100, h = idx - kk * 100;
        Wt[idx] = conv_w[h * 300 + kk];
    } else if (idx < 40000) {
        int j = idx - 30000;
        int h = j / 100, dd = j - h * 100;
        fc2t[j] = fc_w2_w[dd * 100 + h];
    } else if (idx < 91200) {
        Psum[idx - 40000] = 0.f;
    } else if (idx < 127040) {
        int j = idx - 91200;                   // [0, 35840)
        int frag = j >> 9, within = j & 511;
        int l = within >> 3, jj = within & 7;
        int kt = frag / 7, nt = frag % 7;
        int kk = kt * 32 + ((l >> 4) << 3) + jj;
        int h  = nt * 16 + (l & 15);
        ushort v = 0;
        if (kk < 300 && h < 100) v = f2b(conv_w[h * 300 + kk]);
        wpack[j] = v;
    } else if (idx == 127040) {
        *flag_cnt = 0;
    }
}

// ---------------------------------------------------------------------------
// K1: one instance per block (grid 4096), 256 threads = 4 waves, wave = m-tile.
__global__ __launch_bounds__(256, 4)
void k_branch(const int* __restrict__ u_rev, const int* __restrict__ i_rev,
              const float* __restrict__ emb, const ushort* __restrict__ wpack,
              const float* __restrict__ conv_b, const float* __restrict__ fc_w_w,
              const float* __restrict__ fc_w_b, const float* __restrict__ fc_w2_b,
              const float* __restrict__ fc2t, const float* __restrict__ h_r_w,
              const float* __restrict__ h_c_w,
              float* __restrict__ Pbuf, float* __restrict__ Psum,
              float* __restrict__ zdot, float* __restrict__ Pdot,
              float* __restrict__ z_out, int* __restrict__ flag_cnt,
              int* __restrict__ flag_list) {
    __shared__ __align__(16) char smem[36816];
    unsigned int* xw   = (unsigned int*)smem;        // [6656] packed hi|lo X
    ushort* wbuf  = (ushort*)(smem + 26624);         // [3584] one kt-chunk B-frags
    int*    s_tok = (int*)(smem + 33792);            // [52]
    float*  s_vmax= (float*)(smem + 34000);          // [4][100] per-wave col max
    float*  s_maxf= (float*)(smem + 35600);          // [100]
    float*  s_z   = (float*)(smem + 36000);          // [52]
    float*  s_lg  = (float*)(smem + 36208);          // [52]
    float*  s_P   = (float*)(smem + 36416);          // [100]

    const int tid = threadIdx.x, lane = tid & 63, w = tid >> 6;
    const int gi = blockIdx.x;
    const int branch = gi >> 11, inst = gi & 2047;

    // W kt=0 preload (448 uint4; thread covers tid and tid+256)
    const uint4* wp4 = (const uint4*)wpack;
    uint4* wbuf4 = (uint4*)wbuf;
    uint4 st0 = wp4[tid];
    uint4 st1; if (tid < 192) st1 = wp4[256 + tid];

    // tokens
    const int* rev = branch ? i_rev : u_rev;
    if (tid < 52) s_tok[tid] = rev[inst * 52 + tid];
    __syncthreads();

    // gather: 1300 float4 across 256 threads, all loads independent
    {
        const float4* emb4 = (const float4*)emb;
        float4 v[6];
#pragma unroll
        for (int k = 0; k < 6; k++) {
            int idx = tid + (k << 8);
            if (idx < 1300) {
                int s = idx / 25, c = idx - s * 25;
                v[k] = emb4[s_tok[s] * 25 + c];
            }
        }
#pragma unroll
        for (int k = 0; k < 6; k++) {
            int idx = tid + (k << 8);
            if (idx < 1300) {
                uint4 o;
                o.x = pack_hl(v[k].x); o.y = pack_hl(v[k].y);
                o.z = pack_hl(v[k].z); o.w = pack_hl(v[k].w);
                *(uint4*)(xw + idx * 4) = o;
            }
        }
        for (int idx = 1300 + tid; idx < 1664; idx += 256) {
            uint4 z; z.x = 0u; z.y = 0u; z.z = 0u; z.w = 0u;
            *(uint4*)(xw + idx * 4) = z;             // zero pad flat [5200,6656)
        }
    }

    // write kt=0 W chunk, preload kt=1
    wbuf4[tid] = st0;
    if (tid < 192) wbuf4[256 + tid] = st1;
    st0 = wp4[448 + tid];
    if (tid < 192) st1 = wp4[448 + 256 + tid];
    __syncthreads();

    f32x4 acc[7];
#pragma unroll
    for (int nt = 0; nt < 7; nt++) acc[nt] = (f32x4){0.f, 0.f, 0.f, 0.f};

    const int col = lane & 15, quad = lane >> 4, q8 = quad << 3;
    const int mt = w;

    for (int kt = 0; kt < 10; kt++) {
        {
            int e0 = (mt * 16 + col) * 100 + kt * 32 + q8;
            uint4 xa = *(const uint4*)(xw + e0);
            uint4 xb = *(const uint4*)(xw + e0 + 4);
            union AU { short8 s8; uint4 u; } ah, al;
            ah.u.x = (xa.x >> 16) | (xa.y & 0xFFFF0000u);
            ah.u.y = (xa.z >> 16) | (xa.w & 0xFFFF0000u);
            ah.u.z = (xb.x >> 16) | (xb.y & 0xFFFF0000u);
            ah.u.w = (xb.z >> 16) | (xb.w & 0xFFFF0000u);
            al.u.x = (xa.x & 0xFFFFu) | (xa.y << 16);
            al.u.y = (xa.z & 0xFFFFu) | (xa.w << 16);
            al.u.z = (xb.x & 0xFFFFu) | (xb.y << 16);
            al.u.w = (xb.z & 0xFFFFu) | (xb.w << 16);
#pragma unroll
            for (int nt = 0; nt < 7; nt++) {
                union BU { short8 s8; uint4 u4; } b;
                b.u4 = wbuf4[nt * 64 + lane];
                acc[nt] = __builtin_amdgcn_mfma_f32_16x16x32_bf16(al.s8, b.s8, acc[nt], 0, 0, 0);
                acc[nt] = __builtin_amdgcn_mfma_f32_16x16x32_bf16(ah.s8, b.s8, acc[nt], 0, 0, 0);
            }
        }
        __syncthreads();                             // wbuf reads for kt done
        if (kt < 9) {
            wbuf4[tid] = st0;
            if (tid < 192) wbuf4[256 + tid] = st1;
            if (kt < 8) {
                st0 = wp4[(kt + 2) * 448 + tid];
                if (tid < 192) st1 = wp4[(kt + 2) * 448 + 256 + tid];
            }
            __syncthreads();                         // wbuf(kt+1) visible
        }
    }

    // --- epilogue. C/D layout: n=col, m-row = quad*4+j [r6-r8 verified].
    float cb[7], fw[7], vmax[7];
#pragma unroll
    for (int nt = 0; nt < 7; nt++) {
        int h = nt * 16 + col;
        cb[nt] = (h < 100) ? conv_b[h] : 0.f;
        fw[nt] = (h < 100) ? fc_w_w[h] : 0.f;
        vmax[nt] = 0.f;
    }
    const float fcb = fc_w_b[0];

#pragma unroll
    for (int j = 0; j < 4; j++) {
        int p = mt * 16 + quad * 4 + j;
        bool pv = p < 50;
        float part = 0.f;
#pragma unroll
        for (int nt = 0; nt < 7; nt++) {
            float c = acc[nt][j] + cb[nt];
            c = c > 0.f ? c : 0.f;
            part += c * fw[nt];
            if (pv) vmax[nt] = fmaxf(vmax[nt], c);
        }
        part += __shfl_xor(part, 1, 64);
        part += __shfl_xor(part, 2, 64);
        part += __shfl_xor(part, 4, 64);
        part += __shfl_xor(part, 8, 64);
        if (pv && col == 0) {
            float logit = part + fcb;
            float z = rintf(sigmoidf_(logit));
            s_z[p] = z;
            s_lg[p] = logit;
            z_out[branch * 102400 + inst * 50 + p] = z;
        }
    }

    // per-wave column max (over its quads) -> s_vmax[w]
#pragma unroll
    for (int nt = 0; nt < 7; nt++) {
        float m = vmax[nt];
        m = fmaxf(m, __shfl_xor(m, 16, 64));
        m = fmaxf(m, __shfl_xor(m, 32, 64));
        int h = nt * 16 + col;
        if (quad == 0 && h < 100) s_vmax[w * 100 + h] = m;
    }
    __syncthreads();

    if (tid < 100) {
        float mx = fmaxf(fmaxf(s_vmax[tid], s_vmax[100 + tid]),
                         fmaxf(s_vmax[200 + tid], s_vmax[300 + tid]));
        s_maxf[tid] = mx;
    }
    __syncthreads();

    // P matvec (chunk-unrolled, r8-verified order) + Psum atomic
    if (tid < 100) {
        float a = fc_w2_b[tid];
        for (int h0 = 0; h0 < 100; h0 += 10) {
            float wv[10], mxv[10];
#pragma unroll
            for (int t = 0; t < 10; t++) {
                wv[t] = fc2t[(h0 + t) * 100 + tid];
                mxv[t] = s_maxf[h0 + t];
            }
#pragma unroll
            for (int t = 0; t < 10; t++) a += mxv[t] * wv[t];
        }
        Pbuf[gi * 100 + tid] = a;
        s_P[tid] = a;
        atomicAdd(&Psum[(branch * 256 + (inst >> 3)) * 100 + tid], a);
    }
    __syncthreads();

    if (w == 0) {
        float v = (lane < 50) ? s_z[lane] * h_r_w[branch * 50 + lane] : 0.f;
        for (int s = 1; s < 64; s <<= 1) v += __shfl_xor(v, s, 64);
        if (lane == 0) zdot[gi] = v;
    } else if (w == 1) {
        float u = 0.f;
        if (lane < 50) u = s_P[lane] * h_c_w[branch * 100 + lane]
                         + s_P[lane + 50] * h_c_w[branch * 100 + lane + 50];
        for (int s = 1; s < 64; s <<= 1) u += __shfl_xor(u, s, 64);
        if (lane == 0) Pdot[gi] = u;
    } else if (w == 2) {
        // aggregated flag push (r7-verified): one atomic per block
        float lg = 1e9f;
        if (lane < 50) lg = s_lg[lane];
        unsigned long long mb = __ballot(fabsf(lg) < Z_MARGIN);
        int cnt = __popcll(mb);
        int base = 0;
        if (lane == 0 && cnt) base = atomicAdd(flag_cnt, cnt);
        base = __shfl(base, 0, 64);
        if (fabsf(lg) < Z_MARGIN) {
            int rank = __popcll(mb & ((1ull << lane) - 1ull));
            int k = base + rank;
            if (k < FLAG_CAP) flag_list[k] = gi * 50 + lane;
        }
    }
}

// ---------------------------------------------------------------------------
// K2: exact fp32 recompute of flagged z-logits (r7/r8-verified).
__launch_bounds__(256)
__global__ void k_refine(const int* __restrict__ u_rev, const int* __restrict__ i_rev,
                         const float* __restrict__ emb, const float* __restrict__ Wt,
                         const float* __restrict__ conv_b, const float* __restrict__ fc_w_w,
                         const float* __restrict__ fc_w_b, const float* __restrict__ h_r_w,
                         const int* __restrict__ flag_cnt, const int* __restrict__ flag_list,
                         float* __restrict__ z_out, float* __restrict__ zdot) {
    int n = *flag_cnt; if (n > FLAG_CAP) n = FLAG_CAP;
    const int lane = threadIdx.x & 63;
    const int wid = (blockIdx.x * 256 + threadIdx.x) >> 6;
    const int nw = gridDim.x * 4;
    const bool hv = lane < 50;
    const float cb0 = hv ? conv_b[lane] : 0.f;
    const float cb1 = hv ? conv_b[lane + 50] : 0.f;
    const float fw0 = hv ? fc_w_w[lane] : 0.f;
    const float fw1 = hv ? fc_w_w[lane + 50] : 0.f;
    const float fcb = fc_w_b[0];

    for (int e0 = wid * 4; e0 < n; e0 += nw * 4) {
        int gi[4], pos[4];
        bool iv[4];
        float xr[4][5];
#pragma unroll
        for (int m = 0; m < 4; m++) {
            int e = e0 + m;
            iv[m] = e < n;
            int code = iv[m] ? flag_list[e] : 0;
            gi[m] = code / 50; pos[m] = code - gi[m] * 50;
            const int* rev = (gi[m] >> 11) ? i_rev : u_rev;
            int tb = (gi[m] & 2047) * 52 + pos[m];
            int t0 = rev[tb], t1 = rev[tb + 1], t2 = rev[tb + 2];
#pragma unroll
            for (int s = 0; s < 5; s++) {
                int k = s * 64 + lane;
                float v = 0.f;
                if (k < 300) {
                    int r = k / 100, dd = k - r * 100;
                    int t = (r == 0) ? t0 : ((r == 1) ? t1 : t2);
                    v = emb[t * 100 + dd];
                }
                xr[m][s] = v;
            }
        }
        float c0[4], c1[4];
#pragma unroll
        for (int m = 0; m < 4; m++) { c0[m] = cb0; c1[m] = cb1; }
#pragma unroll
        for (int s = 0; s < 5; s++) {
            const int dmax = (s < 4) ? 64 : 44;
#pragma unroll 4
            for (int d2 = 0; d2 < dmax; d2++) {
                int d = s * 64 + d2;
                float w0 = hv ? Wt[d * 100 + lane] : 0.f;
                float w1 = hv ? Wt[d * 100 + lane + 50] : 0.f;
#pragma unroll
                for (int m = 0; m < 4; m++) {
                    float x = __shfl(xr[m][s], d2, 64);
                    c0[m] += x * w0;
                    c1[m] += x * w1;
                }
            }
        }
#pragma unroll
        for (int m = 0; m < 4; m++) {
            float v = fmaxf(c0[m], 0.f) * fw0 + fmaxf(c1[m], 0.f) * fw1;
            for (int s = 1; s < 64; s <<= 1) v += __shfl_xor(v, s, 64);
            if (lane == 0 && iv[m]) {
                int branch = gi[m] >> 11, inst = gi[m] & 2047;
                float z = rintf(sigmoidf_(v + fcb));
                float old = z_out[branch * 102400 + inst * 50 + pos[m]];
                if (z != old) {
                    z_out[branch * 102400 + inst * 50 + pos[m]] = z;
                    atomicAdd(&zdot[gi[m]], (z - old) * h_r_w[branch * 50 + pos[m]]);
                }
            }
        }
    }
}

// ---------------------------------------------------------------------------
// K3: per-edge (verified r5-r8).
__launch_bounds__(256)
__global__ void k_edge(const int* __restrict__ uid, const int* __restrict__ iid,
                       const float* __restrict__ Pbuf, const float* __restrict__ Psum,
                       const float* __restrict__ zdot, const float* __restrict__ Pdot,
                       const float* __restrict__ user_bias, const float* __restrict__ item_bias,
                       const float* __restrict__ global_bias, float* __restrict__ out) {
    int wave = threadIdx.x >> 6, lane = threadIdx.x & 63;
    int e = blockIdx.x * 4 + wave;
    int u = uid[e], i = iid[e];
    int g = lane >> 2, q = lane & 3;
    const float4* prow4; const float4* psum4; float wr, wc;
    if (g < 8) {
        prow4 = (const float4*)(Pbuf + (u * 8 + g) * 100);
        psum4 = (const float4*)(Psum + 25600 + i * 100);
        wr = zdot[u * 8 + g]; wc = Pdot[u * 8 + g];
    } else {
        prow4 = (const float4*)(Pbuf + (2048 + i * 8 + (g - 8)) * 100);
        psum4 = (const float4*)(Psum + u * 100);
        wr = zdot[2048 + i * 8 + (g - 8)]; wc = Pdot[2048 + i * 8 + (g - 8)];
    }
    float part = 0.f;
#pragma unroll
    for (int t = 0; t < 7; t++) {
        int c = q + 4 * t;
        if (c < 25) {
            float4 a = prow4[c], b = psum4[c];
            part += a.x * b.x + a.y * b.y + a.z * b.z + a.w * b.w;
        }
    }
    part += __shfl_xor(part, 1, 64);
    part += __shfl_xor(part, 2, 64);
    float sg = sigmoidf_(part);
    float cr = (q == 0) ? sg * wr : 0.f;
    float cc = (q == 0) ? sg * wc : 0.f;
    for (int s = 4; s < 64; s <<= 1) { cr += __shfl_xor(cr, s, 64); cc += __shfl_xor(cc, s, 64); }
    if (lane == 0) {
        out[e] = cr + user_bias[u] + item_bias[i] + global_bias[0];
        out[20000 + e] = cc;
    }
}

// ---------------------------------------------------------------------------
extern "C" void kernel_launch(void* const* d_in, const int* in_sizes, int n_in,
                              void* d_out, int out_size, void* d_ws, size_t ws_size,
                              hipStream_t stream) {
    const int*   u_rev    = (const int*)d_in[0];
    const int*   i_rev    = (const int*)d_in[1];
    const int*   uid      = (const int*)d_in[2];
    const int*   iid      = (const int*)d_in[3];
    const float* emb      = (const float*)d_in[4];
    const float* conv_w   = (const float*)d_in[5];
    const float* conv_b   = (const float*)d_in[6];
    const float* fc_w_w   = (const float*)d_in[7];
    const float* fc_w_b   = (const float*)d_in[8];
    const float* fc_w2_w  = (const float*)d_in[9];
    const float* fc_w2_b  = (const float*)d_in[10];
    const float* h_r_w    = (const float*)d_in[11];
    const float* h_c_w    = (const float*)d_in[12];
    const float* user_b   = (const float*)d_in[13];
    const float* item_b   = (const float*)d_in[14];
    const float* global_b = (const float*)d_in[15];
    float* out = (float*)d_out;

    float*  ws    = (float*)d_ws;
    float*  Pbuf  = ws;                      // [409600]
    float*  Psum  = ws + 409600;             // [51200]
    float*  zdotb = ws + 460800;             // [4096]
    float*  Pdotb = ws + 464896;             // [4096]
    float*  Wt    = ws + 468992;             // [30000]
    float*  fc2t  = ws + 498992;             // [10000]
    ushort* wpack = (ushort*)(ws + 508992);  // [35840] bf16
    int*    flagc = (int*)(ws + 526912);     // [1]
    int*    flist = (int*)(ws + 526916);     // [204800]

    hipLaunchKernelGGL(k_prep, dim3(497), dim3(256), 0, stream,
                       conv_w, fc_w2_w, Wt, fc2t, Psum, wpack, flagc);
    hipLaunchKernelGGL(k_branch, dim3(4096), dim3(256), 0, stream,
                       u_rev, i_rev, emb, wpack, conv_b, fc_w_w, fc_w_b,
                       fc_w2_b, fc2t, h_r_w, h_c_w,
                       Pbuf, Psum, zdotb, Pdotb, out + 40000, flagc, flist);
    hipLaunchKernelGGL(k_refine, dim3(512), dim3(256), 0, stream,
                       u_rev, i_rev, emb, Wt, conv_b, fc_w_w, fc_w_b, h_r_w,
                       flagc, flist, out + 40000, zdotb);
    hipLaunchKernelGGL(k_edge, dim3(5000), dim3(256), 0, stream,
                       uid, iid, Pbuf, Psum, zdotb, Pdotb,
                       user_b, item_b, global_b, out);
}

// Round 10
// 200.881 us; speedup vs baseline: 7.2839x; 1.0535x over previous
//
#include <hip/hip_runtime.h>
#include <hip/hip_fp16.h>
#include <math.h>

// Model: review-based recommender. ALL float tensors fp32.
// Shapes: VOCAB=20000, D=100, H=100, K=3, N_U=N_I=256, R=8, S=52, Sp=50, E=20000.
// Outputs (fp32, flat): pred_r[20000] @0, pred_c[20000] @20000,
//                       z_u[102400] @40000, z_i[102400] @142400.
//
// R10: conv switched bf16 -> f16 (W error 2^-9 -> 2^-11 rel). X = f16 hi +
// f16(lo*2048) packed u32; lo accumulated in a SEPARATE MFMA accumulator
// (avoids f16 subnormal flush) and combined c = accH + accL/2048.
// Refine margin 2e-3 -> 4e-4: flags ~6500 -> ~1300, k_refine ~50 -> ~8 us.
// K-loop / staging / occupancy structure identical to r9 (measured 68.5 us).

typedef __attribute__((ext_vector_type(8))) _Float16 half8;
typedef __attribute__((ext_vector_type(4))) float f32x4;

__device__ __forceinline__ float sigmoidf_(float x) { return 1.f / (1.f + expf(-x)); }

// pack fp32 -> (f16 hi in top16 | f16((x-hi)*2048) in low16)
__device__ __forceinline__ unsigned int pack_hl16(float x) {
    union { __half h; ushort u; } a, b;
    a.h = __float2half(x);
    float hf = __half2float(a.h);
    b.h = __float2half((x - hf) * 2048.f);
    return ((unsigned int)a.u << 16) | (unsigned int)b.u;
}

#define Z_MARGIN 4e-4f
#define FLAG_CAP 204800

// ---------------------------------------------------------------------------
// K0: prep: Wt[kk=300][h=100] fp32 (refine); fc2t[h][dd]; zero Psum;
// wpack f16 B-frag layout [kt=10][nt=7][lane=64][j=8] (RNE); zero flag cnt.
__global__ void k_prep(const float* __restrict__ conv_w, const float* __restrict__ fc_w2_w,
                       float* __restrict__ Wt, float* __restrict__ fc2t,
                       float* __restrict__ Psum, ushort* __restrict__ wpack,
                       int* __restrict__ flag_cnt) {
    int idx = blockIdx.x * 256 + threadIdx.x;
    if (idx < 30000) {
        int kk = idx / 100, h = idx - kk * 100;
        Wt[idx] = conv_w[h * 300 + kk];
    } else if (idx < 40000) {
        int j = idx - 30000;
        int h = j / 100, dd = j - h * 100;
        fc2t[j] = fc_w2_w[dd * 100 + h];
    } else if (idx < 91200) {
        Psum[idx - 40000] = 0.f;
    } else if (idx < 127040) {
        int j = idx - 91200;                   // [0, 35840)
        int frag = j >> 9, within = j & 511;
        int l = within >> 3, jj = within & 7;
        int kt = frag / 7, nt = frag % 7;
        int kk = kt * 32 + ((l >> 4) << 3) + jj;
        int h  = nt * 16 + (l & 15);
        ushort v = 0;
        if (kk < 300 && h < 100) {
            union { __half h16; ushort u; } t;
            t.h16 = __float2half(conv_w[h * 300 + kk]);
            v = t.u;
        }
        wpack[j] = v;
    } else if (idx == 127040) {
        *flag_cnt = 0;
    }
}

// ---------------------------------------------------------------------------
// K1: one instance per block (grid 4096), 256 threads = 4 waves, wave = m-tile.
__global__ __launch_bounds__(256, 4)
void k_branch(const int* __restrict__ u_rev, const int* __restrict__ i_rev,
              const float* __restrict__ emb, const ushort* __restrict__ wpack,
              const float* __restrict__ conv_b, const float* __restrict__ fc_w_w,
              const float* __restrict__ fc_w_b, const float* __restrict__ fc_w2_b,
              const float* __restrict__ fc2t, const float* __restrict__ h_r_w,
              const float* __restrict__ h_c_w,
              float* __restrict__ Pbuf, float* __restrict__ Psum,
              float* __restrict__ zdot, float* __restrict__ Pdot,
              float* __restrict__ z_out, int* __restrict__ flag_cnt,
              int* __restrict__ flag_list) {
    __shared__ __align__(16) char smem[36816];
    unsigned int* xw   = (unsigned int*)smem;        // [6656] packed hi|lo X (f16)
    ushort* wbuf  = (ushort*)(smem + 26624);         // [3584] one kt-chunk B-frags
    int*    s_tok = (int*)(smem + 33792);            // [52]
    float*  s_vmax= (float*)(smem + 34000);          // [4][100] per-wave col max
    float*  s_maxf= (float*)(smem + 35600);          // [100]
    float*  s_z   = (float*)(smem + 36000);          // [52]
    float*  s_lg  = (float*)(smem + 36208);          // [52]
    float*  s_P   = (float*)(smem + 36416);          // [100]

    const int tid = threadIdx.x, lane = tid & 63, w = tid >> 6;
    const int gi = blockIdx.x;
    const int branch = gi >> 11, inst = gi & 2047;

    // W kt=0 preload (448 uint4; thread covers tid and tid+256)
    const uint4* wp4 = (const uint4*)wpack;
    uint4* wbuf4 = (uint4*)wbuf;
    uint4 st0 = wp4[tid];
    uint4 st1; if (tid < 192) st1 = wp4[256 + tid];

    // tokens
    const int* rev = branch ? i_rev : u_rev;
    if (tid < 52) s_tok[tid] = rev[inst * 52 + tid];
    __syncthreads();

    // gather: 1300 float4 across 256 threads, all loads independent
    {
        const float4* emb4 = (const float4*)emb;
        float4 v[6];
#pragma unroll
        for (int k = 0; k < 6; k++) {
            int idx = tid + (k << 8);
            if (idx < 1300) {
                int s = idx / 25, c = idx - s * 25;
                v[k] = emb4[s_tok[s] * 25 + c];
            }
        }
#pragma unroll
        for (int k = 0; k < 6; k++) {
            int idx = tid + (k << 8);
            if (idx < 1300) {
                uint4 o;
                o.x = pack_hl16(v[k].x); o.y = pack_hl16(v[k].y);
                o.z = pack_hl16(v[k].z); o.w = pack_hl16(v[k].w);
                *(uint4*)(xw + idx * 4) = o;
            }
        }
        for (int idx = 1300 + tid; idx < 1664; idx += 256) {
            uint4 z; z.x = 0u; z.y = 0u; z.z = 0u; z.w = 0u;
            *(uint4*)(xw + idx * 4) = z;             // zero pad flat [5200,6656)
        }
    }

    // write kt=0 W chunk, preload kt=1
    wbuf4[tid] = st0;
    if (tid < 192) wbuf4[256 + tid] = st1;
    st0 = wp4[448 + tid];
    if (tid < 192) st1 = wp4[448 + 256 + tid];
    __syncthreads();

    f32x4 accH[7], accL[7];
#pragma unroll
    for (int nt = 0; nt < 7; nt++) {
        accH[nt] = (f32x4){0.f, 0.f, 0.f, 0.f};
        accL[nt] = (f32x4){0.f, 0.f, 0.f, 0.f};
    }

    const int col = lane & 15, quad = lane >> 4, q8 = quad << 3;
    const int mt = w;

    for (int kt = 0; kt < 10; kt++) {
        {
            int e0 = (mt * 16 + col) * 100 + kt * 32 + q8;
            uint4 xa = *(const uint4*)(xw + e0);
            uint4 xb = *(const uint4*)(xw + e0 + 4);
            union AU { half8 h8; uint4 u; } ah, al;
            ah.u.x = (xa.x >> 16) | (xa.y & 0xFFFF0000u);
            ah.u.y = (xa.z >> 16) | (xa.w & 0xFFFF0000u);
            ah.u.z = (xb.x >> 16) | (xb.y & 0xFFFF0000u);
            ah.u.w = (xb.z >> 16) | (xb.w & 0xFFFF0000u);
            al.u.x = (xa.x & 0xFFFFu) | (xa.y << 16);
            al.u.y = (xa.z & 0xFFFFu) | (xa.w << 16);
            al.u.z = (xb.x & 0xFFFFu) | (xb.y << 16);
            al.u.w = (xb.z & 0xFFFFu) | (xb.w << 16);
#pragma unroll
            for (int nt = 0; nt < 7; nt++) {
                union BU { half8 h8; uint4 u4; } b;
                b.u4 = wbuf4[nt * 64 + lane];
                accL[nt] = __builtin_amdgcn_mfma_f32_16x16x32_f16(al.h8, b.h8, accL[nt], 0, 0, 0);
                accH[nt] = __builtin_amdgcn_mfma_f32_16x16x32_f16(ah.h8, b.h8, accH[nt], 0, 0, 0);
            }
        }
        __syncthreads();                             // wbuf reads for kt done
        if (kt < 9) {
            wbuf4[tid] = st0;
            if (tid < 192) wbuf4[256 + tid] = st1;
            if (kt < 8) {
                st0 = wp4[(kt + 2) * 448 + tid];
                if (tid < 192) st1 = wp4[(kt + 2) * 448 + 256 + tid];
            }
            __syncthreads();                         // wbuf(kt+1) visible
        }
    }

    // --- epilogue. C/D layout: n=col, m-row = quad*4+j [r6-r9 verified;
    // dtype-independent per m121/m123]. c = accH + accL/2048 + bias.
    const float LSC = 4.8828125e-4f;                 // 2^-11
    float cb[7], fw[7], vmax[7];
#pragma unroll
    for (int nt = 0; nt < 7; nt++) {
        int h = nt * 16 + col;
        cb[nt] = (h < 100) ? conv_b[h] : 0.f;
        fw[nt] = (h < 100) ? fc_w_w[h] : 0.f;
        vmax[nt] = 0.f;
    }
    const float fcb = fc_w_b[0];

#pragma unroll
    for (int j = 0; j < 4; j++) {
        int p = mt * 16 + quad * 4 + j;
        bool pv = p < 50;
        float part = 0.f;
#pragma unroll
        for (int nt = 0; nt < 7; nt++) {
            float c = accH[nt][j] + accL[nt][j] * LSC + cb[nt];
            c = c > 0.f ? c : 0.f;
            part += c * fw[nt];
            if (pv) vmax[nt] = fmaxf(vmax[nt], c);
        }
        part += __shfl_xor(part, 1, 64);
        part += __shfl_xor(part, 2, 64);
        part += __shfl_xor(part, 4, 64);
        part += __shfl_xor(part, 8, 64);
        if (pv && col == 0) {
            float logit = part + fcb;
            float z = rintf(sigmoidf_(logit));
            s_z[p] = z;
            s_lg[p] = logit;
            z_out[branch * 102400 + inst * 50 + p] = z;
        }
    }

    // per-wave column max (over its quads) -> s_vmax[w]
#pragma unroll
    for (int nt = 0; nt < 7; nt++) {
        float m = vmax[nt];
        m = fmaxf(m, __shfl_xor(m, 16, 64));
        m = fmaxf(m, __shfl_xor(m, 32, 64));
        int h = nt * 16 + col;
        if (quad == 0 && h < 100) s_vmax[w * 100 + h] = m;
    }
    __syncthreads();

    if (tid < 100) {
        float mx = fmaxf(fmaxf(s_vmax[tid], s_vmax[100 + tid]),
                         fmaxf(s_vmax[200 + tid], s_vmax[300 + tid]));
        s_maxf[tid] = mx;
    }
    __syncthreads();

    // P matvec (chunk-unrolled, verified) + Psum atomic
    if (tid < 100) {
        float a = fc_w2_b[tid];
        for (int h0 = 0; h0 < 100; h0 += 10) {
            float wv[10], mxv[10];
#pragma unroll
            for (int t = 0; t < 10; t++) {
                wv[t] = fc2t[(h0 + t) * 100 + tid];
                mxv[t] = s_maxf[h0 + t];
            }
#pragma unroll
            for (int t = 0; t < 10; t++) a += mxv[t] * wv[t];
        }
        Pbuf[gi * 100 + tid] = a;
        s_P[tid] = a;
        atomicAdd(&Psum[(branch * 256 + (inst >> 3)) * 100 + tid], a);
    }
    __syncthreads();

    if (w == 0) {
        float v = (lane < 50) ? s_z[lane] * h_r_w[branch * 50 + lane] : 0.f;
        for (int s = 1; s < 64; s <<= 1) v += __shfl_xor(v, s, 64);
        if (lane == 0) zdot[gi] = v;
    } else if (w == 1) {
        float u = 0.f;
        if (lane < 50) u = s_P[lane] * h_c_w[branch * 100 + lane]
                         + s_P[lane + 50] * h_c_w[branch * 100 + lane + 50];
        for (int s = 1; s < 64; s <<= 1) u += __shfl_xor(u, s, 64);
        if (lane == 0) Pdot[gi] = u;
    } else if (w == 2) {
        // aggregated flag push (verified): one atomic per block
        float lg = 1e9f;
        if (lane < 50) lg = s_lg[lane];
        unsigned long long mb = __ballot(fabsf(lg) < Z_MARGIN);
        int cnt = __popcll(mb);
        int base = 0;
        if (lane == 0 && cnt) base = atomicAdd(flag_cnt, cnt);
        base = __shfl(base, 0, 64);
        if (fabsf(lg) < Z_MARGIN) {
            int rank = __popcll(mb & ((1ull << lane) - 1ull));
            int k = base + rank;
            if (k < FLAG_CAP) flag_list[k] = gi * 50 + lane;
        }
    }
}

// ---------------------------------------------------------------------------
// K2: exact fp32 recompute of flagged z-logits (r7-r9 verified).
__launch_bounds__(256)
__global__ void k_refine(const int* __restrict__ u_rev, const int* __restrict__ i_rev,
                         const float* __restrict__ emb, const float* __restrict__ Wt,
                         const float* __restrict__ conv_b, const float* __restrict__ fc_w_w,
                         const float* __restrict__ fc_w_b, const float* __restrict__ h_r_w,
                         const int* __restrict__ flag_cnt, const int* __restrict__ flag_list,
                         float* __restrict__ z_out, float* __restrict__ zdot) {
    int n = *flag_cnt; if (n > FLAG_CAP) n = FLAG_CAP;
    const int lane = threadIdx.x & 63;
    const int wid = (blockIdx.x * 256 + threadIdx.x) >> 6;
    const int nw = gridDim.x * 4;
    const bool hv = lane < 50;
    const float cb0 = hv ? conv_b[lane] : 0.f;
    const float cb1 = hv ? conv_b[lane + 50] : 0.f;
    const float fw0 = hv ? fc_w_w[lane] : 0.f;
    const float fw1 = hv ? fc_w_w[lane + 50] : 0.f;
    const float fcb = fc_w_b[0];

    for (int e0 = wid * 4; e0 < n; e0 += nw * 4) {
        int gi[4], pos[4];
        bool iv[4];
        float xr[4][5];
#pragma unroll
        for (int m = 0; m < 4; m++) {
            int e = e0 + m;
            iv[m] = e < n;
            int code = iv[m] ? flag_list[e] : 0;
            gi[m] = code / 50; pos[m] = code - gi[m] * 50;
            const int* rev = (gi[m] >> 11) ? i_rev : u_rev;
            int tb = (gi[m] & 2047) * 52 + pos[m];
            int t0 = rev[tb], t1 = rev[tb + 1], t2 = rev[tb + 2];
#pragma unroll
            for (int s = 0; s < 5; s++) {
                int k = s * 64 + lane;
                float v = 0.f;
                if (k < 300) {
                    int r = k / 100, dd = k - r * 100;
                    int t = (r == 0) ? t0 : ((r == 1) ? t1 : t2);
                    v = emb[t * 100 + dd];
                }
                xr[m][s] = v;
            }
        }
        float c0[4], c1[4];
#pragma unroll
        for (int m = 0; m < 4; m++) { c0[m] = cb0; c1[m] = cb1; }
#pragma unroll
        for (int s = 0; s < 5; s++) {
            const int dmax = (s < 4) ? 64 : 44;
#pragma unroll 4
            for (int d2 = 0; d2 < dmax; d2++) {
                int d = s * 64 + d2;
                float w0 = hv ? Wt[d * 100 + lane] : 0.f;
                float w1 = hv ? Wt[d * 100 + lane + 50] : 0.f;
#pragma unroll
                for (int m = 0; m < 4; m++) {
                    float x = __shfl(xr[m][s], d2, 64);
                    c0[m] += x * w0;
                    c1[m] += x * w1;
                }
            }
        }
#pragma unroll
        for (int m = 0; m < 4; m++) {
            float v = fmaxf(c0[m], 0.f) * fw0 + fmaxf(c1[m], 0.f) * fw1;
            for (int s = 1; s < 64; s <<= 1) v += __shfl_xor(v, s, 64);
            if (lane == 0 && iv[m]) {
                int branch = gi[m] >> 11, inst = gi[m] & 2047;
                float z = rintf(sigmoidf_(v + fcb));
                float old = z_out[branch * 102400 + inst * 50 + pos[m]];
                if (z != old) {
                    z_out[branch * 102400 + inst * 50 + pos[m]] = z;
                    atomicAdd(&zdot[gi[m]], (z - old) * h_r_w[branch * 50 + pos[m]]);
                }
            }
        }
    }
}

// ---------------------------------------------------------------------------
// K3: per-edge (verified r5-r9).
__launch_bounds__(256)
__global__ void k_edge(const int* __restrict__ uid, const int* __restrict__ iid,
                       const float* __restrict__ Pbuf, const float* __restrict__ Psum,
                       const float* __restrict__ zdot, const float* __restrict__ Pdot,
                       const float* __restrict__ user_bias, const float* __restrict__ item_bias,
                       const float* __restrict__ global_bias, float* __restrict__ out) {
    int wave = threadIdx.x >> 6, lane = threadIdx.x & 63;
    int e = blockIdx.x * 4 + wave;
    int u = uid[e], i = iid[e];
    int g = lane >> 2, q = lane & 3;
    const float4* prow4; const float4* psum4; float wr, wc;
    if (g < 8) {
        prow4 = (const float4*)(Pbuf + (u * 8 + g) * 100);
        psum4 = (const float4*)(Psum + 25600 + i * 100);
        wr = zdot[u * 8 + g]; wc = Pdot[u * 8 + g];
    } else {
        prow4 = (const float4*)(Pbuf + (2048 + i * 8 + (g - 8)) * 100);
        psum4 = (const float4*)(Psum + u * 100);
        wr = zdot[2048 + i * 8 + (g - 8)]; wc = Pdot[2048 + i * 8 + (g - 8)];
    }
    float part = 0.f;
#pragma unroll
    for (int t = 0; t < 7; t++) {
        int c = q + 4 * t;
        if (c < 25) {
            float4 a = prow4[c], b = psum4[c];
            part += a.x * b.x + a.y * b.y + a.z * b.z + a.w * b.w;
        }
    }
    part += __shfl_xor(part, 1, 64);
    part += __shfl_xor(part, 2, 64);
    float sg = sigmoidf_(part);
    float cr = (q == 0) ? sg * wr : 0.f;
    float cc = (q == 0) ? sg * wc : 0.f;
    for (int s = 4; s < 64; s <<= 1) { cr += __shfl_xor(cr, s, 64); cc += __shfl_xor(cc, s, 64); }
    if (lane == 0) {
        out[e] = cr + user_bias[u] + item_bias[i] + global_bias[0];
        out[20000 + e] = cc;
    }
}

// ---------------------------------------------------------------------------
extern "C" void kernel_launch(void* const* d_in, const int* in_sizes, int n_in,
                              void* d_out, int out_size, void* d_ws, size_t ws_size,
                              hipStream_t stream) {
    const int*   u_rev    = (const int*)d_in[0];
    const int*   i_rev    = (const int*)d_in[1];
    const int*   uid      = (const int*)d_in[2];
    const int*   iid      = (const int*)d_in[3];
    const float* emb      = (const float*)d_in[4];
    const float* conv_w   = (const float*)d_in[5];
    const float* conv_b   = (const float*)d_in[6];
    const float* fc_w_w   = (const float*)d_in[7];
    const float* fc_w_b   = (const float*)d_in[8];
    const float* fc_w2_w  = (const float*)d_in[9];
    const float* fc_w2_b  = (const float*)d_in[10];
    const float* h_r_w    = (const float*)d_in[11];
    const float* h_c_w    = (const float*)d_in[12];
    const float* user_b   = (const float*)d_in[13];
    const float* item_b   = (const float*)d_in[14];
    const float* global_b = (const float*)d_in[15];
    float* out = (float*)d_out;

    float*  ws    = (float*)d_ws;
    float*  Pbuf  = ws;                      // [409600]
    float*  Psum  = ws + 409600;             // [51200]
    float*  zdotb = ws + 460800;             // [4096]
    float*  Pdotb = ws + 464896;             // [4096]
    float*  Wt    = ws + 468992;             // [30000]
    float*  fc2t  = ws + 498992;             // [10000]
    ushort* wpack = (ushort*)(ws + 508992);  // [35840] f16
    int*    flagc = (int*)(ws + 526912);     // [1]
    int*    flist = (int*)(ws + 526916);     // [204800]

    hipLaunchKernelGGL(k_prep, dim3(497), dim3(256), 0, stream,
                       conv_w, fc_w2_w, Wt, fc2t, Psum, wpack, flagc);
    hipLaunchKernelGGL(k_branch, dim3(4096), dim3(256), 0, stream,
                       u_rev, i_rev, emb, wpack, conv_b, fc_w_w, fc_w_b,
                       fc_w2_b, fc2t, h_r_w, h_c_w,
                       Pbuf, Psum, zdotb, Pdotb, out + 40000, flagc, flist);
    hipLaunchKernelGGL(k_refine, dim3(128), dim3(256), 0, stream,
                       u_rev, i_rev, emb, Wt, conv_b, fc_w_w, fc_w_b, h_r_w,
                       flagc, flist, out + 40000, zdotb);
    hipLaunchKernelGGL(k_edge, dim3(5000), dim3(256), 0, stream,
                       uid, iid, Pbuf, Psum, zdotb, Pdotb,
                       user_b, item_b, global_b, out);
}